// Round 7
// baseline (542.113 us; speedup 1.0000x reference)
//
#include <hip/hip_runtime.h>
#include <math.h>

// Problem constants: B=8, N=1024, FIN=FOUT=512, H=8, HD=64, BH=64

typedef __attribute__((ext_vector_type(8))) short short8;    // 8 bf16 (4 VGPRs)
typedef __attribute__((ext_vector_type(4))) float floatx4;   // MFMA C/D

// Workspace byte offsets (~89 MB).
// Overlays: VT overlays XH (dead after proj); QLV/KLV overlay VRAW (vtrans
// runs BEFORE quant2); PS overlays QRAW (dead after quant2).
#define OB_WPT   0ull           // 4718592   wph/wpm/wpl bf16 planes [o=1536][k=512]
#define OB_XT    4718592ull     // 25165824  xh/xm/xl bf16 planes [t=8192][k=512]
#define OB_VT    OB_XT          // 8388608   v^T bf16 (overlay, after proj)
#define OB_QRAW  36700160ull    // 16777216  q raw fp32 (b,h,n,d)
#define OB_PS    OB_QRAW        // 2097152   partial (m,l) x4 (overlay)
#define OB_KRAW  53477376ull    // 16777216  k raw fp32
#define OB_VRAW  70254592ull    // 16777216  v raw fp32
#define OB_QLV   70254592ull    // 8388608   q levels bf16 (overlay vraw lo)
#define OB_KLV   78643200ull    // 8388608   k levels bf16 (overlay vraw hi, SWIZZLED)
#define OB_RS    87031808ull    // 524288    rowstats float2
#define OB_BM    87556096ull    // 1048576   adj bitmask u64
#define OB_AMAX  88604672ull    // 16        amax_q, amax_k, amax_attn

__device__ __forceinline__ unsigned short bf16_rne(float f) {
    unsigned int u = __float_as_uint(f);
    unsigned int r = u + 0x7fffu + ((u >> 16) & 1u);
    return (unsigned short)(r >> 16);
}
__device__ __forceinline__ float bf16_to_f(unsigned short h) {
    return __uint_as_float(((unsigned int)h) << 16);
}
// exact for values already representable in bf16 (integer levels |x|<=127)
__device__ __forceinline__ unsigned short bf16_exact(float f) {
    return (unsigned short)(__float_as_uint(f) >> 16);
}

// async global->LDS, 16 B per lane; gptr is per-lane, LDS dest = base+lane*16
__device__ __forceinline__ void dma16u(const unsigned short* g, unsigned short* l) {
    __builtin_amdgcn_global_load_lds(
        (__attribute__((address_space(1))) void*)(void*)g,
        (__attribute__((address_space(3))) void*)(void*)l, 16, 0, 0);
}

// ---------------------------------------------------------------------------
// K0: adjacency (8,1024,1024) i32 -> bitmask (8,1024,16) u64. One word/wave.
// ---------------------------------------------------------------------------
__global__ __launch_bounds__(256) void adj_bits_k(
    const int* __restrict__ adj, unsigned long long* __restrict__ bm)
{
    int tid = threadIdx.x;
    int wv = tid >> 6, lane = tid & 63;
    size_t word = (size_t)blockIdx.x * 4 + wv;       // 131072 words total
    int a = adj[word * 64 + lane];
    unsigned long long m = __ballot(a != 0);
    if (lane == 0) bm[word] = m;
}

// ---------------------------------------------------------------------------
// K0b: x fp32 [8192][512] -> hi/mid/lo bf16 planes (cascaded rne splits).
// ---------------------------------------------------------------------------
__global__ __launch_bounds__(256) void splitx_k(
    const float* __restrict__ x, unsigned short* __restrict__ xh,
    unsigned short* __restrict__ xm, unsigned short* __restrict__ xl)
{
    int i = blockIdx.x * 256 + threadIdx.x;          // 1048576 float4s
    float4 v = ((const float4*)x)[i];
    ushort4 h, m, l;
    float r1, r2;
    h.x = bf16_rne(v.x); r1 = v.x - bf16_to_f(h.x);
    m.x = bf16_rne(r1);  r2 = r1 - bf16_to_f(m.x);  l.x = bf16_rne(r2);
    h.y = bf16_rne(v.y); r1 = v.y - bf16_to_f(h.y);
    m.y = bf16_rne(r1);  r2 = r1 - bf16_to_f(m.y);  l.y = bf16_rne(r2);
    h.z = bf16_rne(v.z); r1 = v.z - bf16_to_f(h.z);
    m.z = bf16_rne(r1);  r2 = r1 - bf16_to_f(m.z);  l.z = bf16_rne(r2);
    h.w = bf16_rne(v.w); r1 = v.w - bf16_to_f(h.w);
    m.w = bf16_rne(r1);  r2 = r1 - bf16_to_f(m.w);  l.w = bf16_rne(r2);
    ((ushort4*)xh)[i] = h;
    ((ushort4*)xm)[i] = m;
    ((ushort4*)xl)[i] = l;
}

// ---------------------------------------------------------------------------
// K1: all three DoRA-merged weights -> hi/mid/lo bf16 planes wp{h,m,l}[o][k].
// ---------------------------------------------------------------------------
__global__ __launch_bounds__(256) void build_wp3_k(
    const float* __restrict__ W_q, const float* __restrict__ A_q,
    const float* __restrict__ B_q, const float* __restrict__ m_q,
    const float* __restrict__ W_k, const float* __restrict__ A_k,
    const float* __restrict__ B_k, const float* __restrict__ m_k,
    const float* __restrict__ W_v, const float* __restrict__ A_v,
    const float* __restrict__ B_v, const float* __restrict__ m_v,
    unsigned short* __restrict__ wph, unsigned short* __restrict__ wpm,
    unsigned short* __restrict__ wpl)
{
    __shared__ float brow[16];
    __shared__ __align__(16) float wd[512];
    __shared__ float red[5];
    int o = blockIdx.x;
    int mtx = blockIdx.y;
    const float* W   = mtx == 0 ? W_q : (mtx == 1 ? W_k : W_v);
    const float* A   = mtx == 0 ? A_q : (mtx == 1 ? A_k : A_v);
    const float* Bm  = mtx == 0 ? B_q : (mtx == 1 ? B_k : B_v);
    const float* mag = mtx == 0 ? m_q : (mtx == 1 ? m_k : m_v);
    int ocol = mtx * 512 + o;
    int tid = threadIdx.x;
    if (tid < 16) brow[tid] = Bm[o * 16 + tid];
    __syncthreads();
    float ss = 0.f;
    for (int i = tid; i < 512; i += 256) {
        float acc = W[o * 512 + i];
#pragma unroll
        for (int r = 0; r < 16; ++r) acc = fmaf(brow[r], A[r * 512 + i], acc);
        wd[i] = acc;
        ss = fmaf(acc, acc, ss);
    }
#pragma unroll
    for (int off = 32; off > 0; off >>= 1) ss += __shfl_down(ss, off);
    int lane = tid & 63, wv = tid >> 6;
    if (lane == 0) red[wv] = ss;
    __syncthreads();
    if (tid == 0) red[4] = mag[o] / sqrtf(red[0] + red[1] + red[2] + red[3]);
    __syncthreads();
    float scl = red[4];
    for (int i = tid; i < 512; i += 256) {
        float v = wd[i] * scl;
        unsigned short h = bf16_rne(v);
        float r1 = v - bf16_to_f(h);
        unsigned short m = bf16_rne(r1);
        float r2 = r1 - bf16_to_f(m);
        wph[(size_t)ocol * 512 + i] = h;
        wpm[(size_t)ocol * 512 + i] = m;
        wpl[(size_t)ocol * 512 + i] = bf16_rne(r2);
    }
}

// ---------------------------------------------------------------------------
// K2: triple-split bf16 MFMA projection — 512-thread 8-wave version.
// Same double-buffer + prefetch + vmcnt(0)+s_barrier sync pattern as the
// (correct but occupancy-starved) round-5 kernel, but 8 waves/block over the
// 128x128 tile (each wave 32x64, acc[2][4]) -> 2 waves/SIMD, and per-step
// per-wave work drops to 6 DMA + 18 ds_read + 48 MFMA. Per-CU MFMA work
// (~1860 cyc/step) hides staging latency; drain is then free.
// LDS 96 KB -> 1 block/CU (8 waves). Per-element K/term order identical to
// rounds 3/4 -> q/k/v bit-identical. XCD-chunked remap kept.
// ---------------------------------------------------------------------------
__global__ __launch_bounds__(512) void proj_mfma_k(
    const unsigned short* __restrict__ xh, const unsigned short* __restrict__ xm,
    const unsigned short* __restrict__ xl,
    const unsigned short* __restrict__ wph, const unsigned short* __restrict__ wpm,
    const unsigned short* __restrict__ wpl,
    float* __restrict__ qraw, float* __restrict__ kraw, float* __restrict__ vraw,
    unsigned int* __restrict__ amax)
{
    __shared__ __align__(16) unsigned short Ah[2][128][32];
    __shared__ __align__(16) unsigned short Am[2][128][32];
    __shared__ __align__(16) unsigned short Al[2][128][32];
    __shared__ __align__(16) unsigned short Bh[2][128][32];
    __shared__ __align__(16) unsigned short Bmd[2][128][32];
    __shared__ __align__(16) unsigned short Bl[2][128][32];
    __shared__ float redmax[8];
    int tid = threadIdx.x;
    int lane = tid & 63, w = tid >> 6;         // 8 waves
    // XCD-chunked remap (bijective on [0,768))
    int g = blockIdx.y * 64 + blockIdx.x;
    int xcd = g & 7, slot = g >> 3;            // slot in [0,96)
    int tt = (xcd << 3) | (slot / 12);         // t-tile 0..63
    int oo = slot - (slot / 12) * 12;          // o-tile 0..11
    int t0 = tt * 128;
    int o0 = oo * 128;
    int mtx = o0 >> 9;                         // 0=q 1=k 2=v (128 | 512)
    float* dst = mtx == 0 ? qraw : (mtx == 1 ? kraw : vraw);
    int wt0 = (w >> 1) * 32;                   // wave's t sub-tile (32 rows)
    int wo0 = (w & 1) * 64;                    // wave's o sub-tile (64 cols)

    floatx4 acc[2][4];
#pragma unroll
    for (int mi = 0; mi < 2; ++mi)
#pragma unroll
        for (int nj = 0; nj < 4; ++nj) acc[mi][nj] = (floatx4){0.f, 0.f, 0.f, 0.f};

    // staging: wave w owns rows [w*16, w*16+16) of each 128x32 tile; one
    // dma16u per plane per step (64 lanes x 16B = 16 rows of 64B).
    int srow = w * 16 + (lane >> 2);
    int scol = (lane & 3) * 8;
    const unsigned short* gAh = xh  + (size_t)(t0 + srow) * 512 + scol;
    const unsigned short* gAm = xm  + (size_t)(t0 + srow) * 512 + scol;
    const unsigned short* gAl = xl  + (size_t)(t0 + srow) * 512 + scol;
    const unsigned short* gBh = wph + (size_t)(o0 + srow) * 512 + scol;
    const unsigned short* gBm = wpm + (size_t)(o0 + srow) * 512 + scol;
    const unsigned short* gBl = wpl + (size_t)(o0 + srow) * 512 + scol;

    int fr = lane & 15;                        // fragment row/col index
    int fk = (lane >> 4) * 8;                  // fragment k offset

#define STAGE(bf, kidx) do {                                           \
        size_t ko_ = (size_t)(kidx) * 32;                              \
        dma16u(gAh + ko_, &Ah[bf][w * 16][0]);                         \
        dma16u(gAm + ko_, &Am[bf][w * 16][0]);                         \
        dma16u(gAl + ko_, &Al[bf][w * 16][0]);                         \
        dma16u(gBh + ko_, &Bh[bf][w * 16][0]);                         \
        dma16u(gBm + ko_, &Bmd[bf][w * 16][0]);                        \
        dma16u(gBl + ko_, &Bl[bf][w * 16][0]);                         \
    } while (0)

    // prologue: stage tile 0, drain, barrier
    STAGE(0, 0);
    __asm__ volatile("s_waitcnt vmcnt(0)" ::: "memory");
    __builtin_amdgcn_s_barrier();

    for (int kt = 0; kt < 16; ++kt) {
        int buf = kt & 1;
        if (kt + 1 < 16) STAGE(buf ^ 1, kt + 1);   // prefetch flies under MFMA

        short8 ah[2], am[2], al[2];
#pragma unroll
        for (int mi = 0; mi < 2; ++mi) {
            int ar = wt0 + mi * 16 + fr;
            ah[mi] = *(const short8*)&Ah[buf][ar][fk];
            am[mi] = *(const short8*)&Am[buf][ar][fk];
            al[mi] = *(const short8*)&Al[buf][ar][fk];
        }
#pragma unroll
        for (int nj = 0; nj < 4; ++nj) {
            int br = wo0 + nj * 16 + fr;
            short8 bh = *(const short8*)&Bh[buf][br][fk];
            short8 bm = *(const short8*)&Bmd[buf][br][fk];
            short8 bl = *(const short8*)&Bl[buf][br][fk];
#pragma unroll
            for (int mi = 0; mi < 2; ++mi) {
                acc[mi][nj] = __builtin_amdgcn_mfma_f32_16x16x32_bf16(ah[mi], bh, acc[mi][nj], 0, 0, 0);
                acc[mi][nj] = __builtin_amdgcn_mfma_f32_16x16x32_bf16(ah[mi], bm, acc[mi][nj], 0, 0, 0);
                acc[mi][nj] = __builtin_amdgcn_mfma_f32_16x16x32_bf16(am[mi], bh, acc[mi][nj], 0, 0, 0);
                acc[mi][nj] = __builtin_amdgcn_mfma_f32_16x16x32_bf16(ah[mi], bl, acc[mi][nj], 0, 0, 0);
                acc[mi][nj] = __builtin_amdgcn_mfma_f32_16x16x32_bf16(al[mi], bh, acc[mi][nj], 0, 0, 0);
                acc[mi][nj] = __builtin_amdgcn_mfma_f32_16x16x32_bf16(am[mi], bm, acc[mi][nj], 0, 0, 0);
            }
        }
        // own 6 prefetch loads were issued ~full step ago -> drain is cheap
        __asm__ volatile("s_waitcnt vmcnt(0)" ::: "memory");
        __builtin_amdgcn_s_barrier();
    }
#undef STAGE

    // epilogue: D[row=(lane>>4)*4+r][col=lane&15]; scatter to (b,h,n,d) raw.
    float mx = 0.f;
#pragma unroll
    for (int mi = 0; mi < 2; ++mi) {
#pragma unroll
        for (int r = 0; r < 4; ++r) {
            int t = t0 + wt0 + mi * 16 + (lane >> 4) * 4 + r;
            int b = t >> 10, n = t & 1023;
#pragma unroll
            for (int nj = 0; nj < 4; ++nj) {
                int o = o0 + wo0 + nj * 16 + fr;
                int h = (o >> 6) & 7, d = o & 63;
                float val = acc[mi][nj][r];
                dst[((size_t)(b * 8 + h) * 1024 + n) * 64 + d] = val;
                mx = fmaxf(mx, fabsf(val));
            }
        }
    }
    if (mtx < 2) {
#pragma unroll
        for (int off = 32; off > 0; off >>= 1) mx = fmaxf(mx, __shfl_down(mx, off));
        if ((tid & 63) == 0) redmax[tid >> 6] = mx;
        __syncthreads();
        if (tid == 0) {
            float m2 = redmax[0];
#pragma unroll
            for (int i = 1; i < 8; ++i) m2 = fmaxf(m2, redmax[i]);
            atomicMax(&amax[mtx], __float_as_uint(m2));
        }
    }
}

// ---------------------------------------------------------------------------
// K2b: q AND k raw fp32 -> int8 levels as exact bf16 (grid.y=2).
// q written LINEAR; k written XOR-SWIZZLED within each 128 B row
// (chunk16 ^= n&7) so attn kernels can DMA-stage linearly and ds_read
// bank-conflict-free (T2 both-sides rule).
// ---------------------------------------------------------------------------
__global__ __launch_bounds__(256) void quant2_k(
    const float* __restrict__ qraw, const float* __restrict__ kraw,
    const unsigned int* __restrict__ amax,
    unsigned short* __restrict__ qlv, unsigned short* __restrict__ klv)
{
    int m = blockIdx.y;
    const float* raw = m ? kraw : qraw;
    unsigned short* lv = m ? klv : qlv;
    float scale = fmaxf(__uint_as_float(amax[m]) / 127.f, 1e-8f);
    int i = blockIdx.x * 256 + threadIdx.x;          // n4 = 1048576
    float4 v = ((const float4*)raw)[i];
    float l0 = fminf(fmaxf(rintf(v.x / scale), -127.f), 127.f);
    float l1 = fminf(fmaxf(rintf(v.y / scale), -127.f), 127.f);
    float l2 = fminf(fmaxf(rintf(v.z / scale), -127.f), 127.f);
    float l3 = fminf(fmaxf(rintf(v.w / scale), -127.f), 127.f);
    ushort4 o;
    o.x = bf16_exact(l0); o.y = bf16_exact(l1);
    o.z = bf16_exact(l2); o.w = bf16_exact(l3);
    int idx4 = i;
    if (m) {
        int elem0 = i * 4;
        int d0 = elem0 & 63;
        int n = (elem0 >> 6) & 1023;
        int dp = (d0 & 7) | ((((d0 >> 3) ^ n) & 7) << 3);
        idx4 = (elem0 - d0 + dp) >> 2;
    }
    ((ushort4*)lv)[idx4] = o;
}

// ---------------------------------------------------------------------------
// K2c: v (bh,n,64) fp32 -> transposed bf16 (bh,d=64,m=1024), XOR-SWIZZLED
// within each 64-col (128 B) m-block: chunk16 ^= d&7 (matches attn_out's
// staged-tile read pattern).
// ---------------------------------------------------------------------------
__global__ __launch_bounds__(256) void vtrans_k(
    const float* __restrict__ vb, unsigned short* __restrict__ vt)
{
    __shared__ float ls[64][69];
    int tid = threadIdx.x;
    int mt = blockIdx.x, bh = blockIdx.y;
#pragma unroll
    for (int l = 0; l < 4; ++l) {
        int idx = l * 256 + tid;
        int r = idx >> 4, c4 = idx & 15;
        float4 v = *(const float4*)(vb + (size_t)(bh * 1024 + mt * 64 + r) * 64 + c4 * 4);
        ls[r][c4 * 4 + 0] = v.x; ls[r][c4 * 4 + 1] = v.y;
        ls[r][c4 * 4 + 2] = v.z; ls[r][c4 * 4 + 3] = v.w;
    }
    __syncthreads();
#pragma unroll
    for (int l = 0; l < 4; ++l) {
        int idx = l * 256 + tid;
        int d = idx >> 4, mg = idx & 15;
        ushort4 hi;
        hi.x = bf16_rne(ls[mg * 4 + 0][d]);
        hi.y = bf16_rne(ls[mg * 4 + 1][d]);
        hi.z = bf16_rne(ls[mg * 4 + 2][d]);
        hi.w = bf16_rne(ls[mg * 4 + 3][d]);
        int ml = mg * 4;                                 // local m in [0,64)
        int mlp = (ml & 7) | ((((ml >> 3) ^ d) & 7) << 3);
        *(ushort4*)(vt + (size_t)(bh * 64 + d) * 1024 + mt * 64 + mlp) = hi;
    }
}

// ---------------------------------------------------------------------------
// K3a: MFMA scores + bitmask + online (m,l) over a column QUARTER.
// K tiles STAGED in LDS (double-buffered, linear DMA of the pre-swizzled
// klv) shared by all 4 waves -> 4x fewer global K reads; swizzled ds_read
// is bank-conflict-free. Grid (16 qt, 64 bh, 4 quarter), XCD-chunked remap.
// ---------------------------------------------------------------------------
__global__ __launch_bounds__(256) void attn_stats_k(
    const unsigned short* __restrict__ qlv, const unsigned short* __restrict__ klv,
    const unsigned long long* __restrict__ bm, const unsigned int* __restrict__ amax,
    float2* __restrict__ psums)
{
    __shared__ __align__(16) unsigned short Ks[2][64][64];   // 16 KB dbuf
    int tid = threadIdx.x;
    int lane = tid & 63, w = tid >> 6;
    int m_ = lane & 15, quad = lane >> 4;
    // remap (bijective on [0,4096))
    int g = blockIdx.z * 1024 + blockIdx.y * 16 + blockIdx.x;
    int xcd = g & 7, slot = g >> 3;            // slot in [0,512)
    int bh = (xcd << 3) | (slot >> 6);
    int rem = slot & 63;
    int qt = rem >> 2, qtr = rem & 3;
    int b = bh >> 3;
    int rowbase = qt * 64 + w * 16;
    float sq = fmaxf(__uint_as_float(amax[0]) / 127.f, 1e-8f);
    float sk = fmaxf(__uint_as_float(amax[1]) / 127.f, 1e-8f);
    float ss = sq * sk;

    const unsigned short* qp = qlv + ((size_t)bh * 1024 + rowbase + m_) * 64;
    short8 Aq0 = *(const short8*)(qp + quad * 8);
    short8 Aq1 = *(const short8*)(qp + 32 + quad * 8);
    const unsigned long long* bmb = bm + ((size_t)b * 1024 + rowbase) * 16;

    // staging: wave w stages tile rows [w*16, w*16+16); lane l -> row l>>3,
    // 16B chunk l&7 (linear, matches LDS dest base+lane*16)
    const unsigned short* gK = klv + ((size_t)bh * 1024 + w * 16) * 64 + lane * 8;
    int sw0 = ((quad ^ m_) & 7) << 3;          // B0 swizzled col (row parity m_&7)
    int sw1 = (((4 + quad) ^ m_) & 7) << 3;    // B1

    float mrun[4], lrun[4];
#pragma unroll
    for (int r = 0; r < 4; ++r) { mrun[r] = -1e9f; lrun[r] = 0.f; }

    {
        size_t off = (size_t)(qtr * 4) * 4096;
        dma16u(gK + off,       &Ks[0][w * 16][0]);
        dma16u(gK + off + 512, &Ks[0][w * 16 + 8][0]);
    }
    __asm__ volatile("s_waitcnt vmcnt(0)" ::: "memory");
    __builtin_amdgcn_s_barrier();

    for (int ci = 0; ci < 4; ++ci) {
        int c = qtr * 4 + ci;
        int buf = ci & 1;
        if (ci < 3) {
            size_t off = (size_t)(c + 1) * 4096;
            dma16u(gK + off,       &Ks[buf ^ 1][w * 16][0]);
            dma16u(gK + off + 512, &Ks[buf ^ 1][w * 16 + 8][0]);
        }
        unsigned long long mk[4];
#pragma unroll
        for (int r = 0; r < 4; ++r) mk[r] = bmb[(quad * 4 + r) * 16 + c];
        float sv[4][4];
#pragma unroll
        for (int s = 0; s < 4; ++s) {
            short8 B0 = *(const short8*)&Ks[buf][s * 16 + m_][sw0];
            short8 B1 = *(const short8*)&Ks[buf][s * 16 + m_][sw1];
            floatx4 Cv = {0.f, 0.f, 0.f, 0.f};
            Cv = __builtin_amdgcn_mfma_f32_16x16x32_bf16(Aq0, B0, Cv, 0, 0, 0);
            Cv = __builtin_amdgcn_mfma_f32_16x16x32_bf16(Aq1, B1, Cv, 0, 0, 0);
            int colbit = s * 16 + m_;
#pragma unroll
            for (int r = 0; r < 4; ++r)
                sv[r][s] = ((mk[r] >> colbit) & 1ull) ? Cv[r] * ss : -1e9f;
        }
#pragma unroll
        for (int r = 0; r < 4; ++r) {
            float tm = fmaxf(fmaxf(sv[r][0], sv[r][1]), fmaxf(sv[r][2], sv[r][3]));
            float mn = fmaxf(mrun[r], tm);
            float e = __expf(sv[r][0] - mn) + __expf(sv[r][1] - mn)
                    + __expf(sv[r][2] - mn) + __expf(sv[r][3] - mn);
            lrun[r] = fmaf(lrun[r], __expf(mrun[r] - mn), e);
            mrun[r] = mn;
        }
        __asm__ volatile("s_waitcnt vmcnt(0)" ::: "memory");
        __builtin_amdgcn_s_barrier();
    }

#pragma unroll
    for (int r = 0; r < 4; ++r) {
        float m = mrun[r], l = lrun[r];
#pragma unroll
        for (int off = 1; off < 16; off <<= 1) {
            float mo = __shfl_xor(m, off);
            float lo = __shfl_xor(l, off);
            float mn = fmaxf(m, mo);
            l = l * __expf(m - mn) + lo * __expf(mo - mn);
            m = mn;
        }
        if (m_ == 0)
            psums[(size_t)qtr * 65536 + (size_t)bh * 1024 + rowbase + quad * 4 + r] =
                make_float2(m, l);
    }
}

// ---------------------------------------------------------------------------
// K3a2: merge 4 quarter-(m,l) into rowstats; global attn amax = max 1/l.
// ---------------------------------------------------------------------------
__global__ __launch_bounds__(256) void stats_merge_k(
    const float2* __restrict__ ps, float2* __restrict__ rowstats,
    unsigned int* __restrict__ amax_attn)
{
    int row = blockIdx.x * 256 + threadIdx.x;        // 65536 rows
    float2 a = ps[row];
    float m = a.x, l = a.y;
#pragma unroll
    for (int q = 1; q < 4; ++q) {
        float2 bq = ps[(size_t)q * 65536 + row];
        float mn = fmaxf(m, bq.x);
        l = l * __expf(m - mn) + bq.y * __expf(bq.x - mn);
        m = mn;
    }
    rowstats[row] = make_float2(m, l);
    float inv = 1.0f / l;
#pragma unroll
    for (int off = 1; off < 64; off <<= 1) inv = fmaxf(inv, __shfl_xor(inv, off));
    if ((threadIdx.x & 63) == 0) atomicMax(amax_attn, __float_as_uint(inv));
}

// ---------------------------------------------------------------------------
// K3b: full-row attn+out with K AND V tiles STAGED in LDS (double-buffered
// linear DMA of pre-swizzled klv/vt, shared by 4 waves -> 4x fewer global
// reads). Scores bit-identical; P quantize + coalesced attn writes + fused
// P@V MFMA; direct out store. XCD-chunked remap.
// LDS: Ks 16K + Vs 16K + pl 17.4K = 49.4 KB -> 3 blocks/CU.
// ---------------------------------------------------------------------------
__global__ __launch_bounds__(256) void attn_out_k(
    const unsigned short* __restrict__ qlv, const unsigned short* __restrict__ klv,
    const unsigned short* __restrict__ vt,
    const unsigned long long* __restrict__ bm, const unsigned int* __restrict__ amax,
    const float2* __restrict__ rowstats,
    float* __restrict__ attn, float* __restrict__ out)
{
    __shared__ __align__(16) unsigned short Ks[2][64][64];   // 16 KB
    __shared__ __align__(16) unsigned short Vs[2][64][64];   // 16 KB
    __shared__ unsigned short pl[4][2][16][68];              // per-wave P dbuf
    int tid = threadIdx.x;
    int lane = tid & 63, w = tid >> 6;
    int m_ = lane & 15, quad = lane >> 4;
    // remap (bijective on [0,1024))
    int g = blockIdx.y * 16 + blockIdx.x;
    int xcd = g & 7, slot = g >> 3;            // slot in [0,128)
    int bh = (xcd << 3) | (slot >> 4);
    int qt = slot & 15;
    int b = bh >> 3, h = bh & 7;
    int rowbase = qt * 64 + w * 16;
    float sq = fmaxf(__uint_as_float(amax[0]) / 127.f, 1e-8f);
    float sk = fmaxf(__uint_as_float(amax[1]) / 127.f, 1e-8f);
    float ss = sq * sk;
    float sa = fmaxf(__uint_as_float(amax[2]) / 127.f, 1e-8f);
    float inv_sa = 1.0f / sa;

    const unsigned short* qp = qlv + ((size_t)bh * 1024 + rowbase + m_) * 64;
    short8 Aq0 = *(const short8*)(qp + quad * 8);
    short8 Aq1 = *(const short8*)(qp + 32 + quad * 8);
    const unsigned long long* bmb = bm + ((size_t)b * 1024 + rowbase) * 16;

    // staging pointers: wave w stages tile rows [w*16, w*16+16)
    const unsigned short* gK  = klv + ((size_t)bh * 1024 + w * 16) * 64 + lane * 8;
    const unsigned short* gV  = vt + ((size_t)(bh * 64 + w * 16 + (lane >> 3))) * 1024 + (lane & 7) * 8;
    const unsigned short* gV2 = gV + 8 * 1024;
    int sw0 = ((quad ^ m_) & 7) << 3;
    int sw1 = (((4 + quad) ^ m_) & 7) << 3;

    float mrow[4], rlr[4];
#pragma unroll
    for (int r = 0; r < 4; ++r) {
        float2 st = rowstats[(size_t)bh * 1024 + rowbase + quad * 4 + r];
        mrow[r] = st.x;
        rlr[r] = 1.0f / st.y;
    }
    floatx4 acc[4];
#pragma unroll
    for (int r = 0; r < 4; ++r) acc[r] = (floatx4){0.f, 0.f, 0.f, 0.f};

    float* attn_b = attn + ((size_t)bh << 20);

#define STG(bf, cc) do {                                                  \
        dma16u(gK + (size_t)(cc) * 4096,       &Ks[bf][w * 16][0]);       \
        dma16u(gK + (size_t)(cc) * 4096 + 512, &Ks[bf][w * 16 + 8][0]);   \
        dma16u(gV + (cc) * 64,                 &Vs[bf][w * 16][0]);       \
        dma16u(gV2 + (cc) * 64,                &Vs[bf][w * 16 + 8][0]);   \
    } while (0)

    STG(0, 0);
    __asm__ volatile("s_waitcnt vmcnt(0)" ::: "memory");
    __builtin_amdgcn_s_barrier();

    for (int ci = 0; ci < 16; ++ci) {
        int c = ci;
        int buf = ci & 1;
        if (ci + 1 < 16) STG(buf ^ 1, ci + 1);
        // V fragments from LDS (buf ready via prior barrier)
        short8 Vb0[4], Vb1[4];
#pragma unroll
        for (int dt = 0; dt < 4; ++dt) {
            Vb0[dt] = *(const short8*)&Vs[buf][dt * 16 + m_][sw0];
            Vb1[dt] = *(const short8*)&Vs[buf][dt * 16 + m_][sw1];
        }
        unsigned long long mk[4];
#pragma unroll
        for (int r = 0; r < 4; ++r) mk[r] = bmb[(quad * 4 + r) * 16 + c];
        unsigned short* plw = &pl[w][ci & 1][0][0];
#pragma unroll
        for (int s = 0; s < 4; ++s) {
            short8 B0 = *(const short8*)&Ks[buf][s * 16 + m_][sw0];
            short8 B1 = *(const short8*)&Ks[buf][s * 16 + m_][sw1];
            floatx4 Cv = {0.f, 0.f, 0.f, 0.f};
            Cv = __builtin_amdgcn_mfma_f32_16x16x32_bf16(Aq0, B0, Cv, 0, 0, 0);
            Cv = __builtin_amdgcn_mfma_f32_16x16x32_bf16(Aq1, B1, Cv, 0, 0, 0);
            int colbit = s * 16 + m_;
#pragma unroll
            for (int r = 0; r < 4; ++r) {
                float sval = ((mk[r] >> colbit) & 1ull) ? Cv[r] * ss : -1e9f;
                float p = __expf(sval - mrow[r]) * rlr[r];   // round-3 op order
                float lv = fminf(rintf(p * inv_sa), 127.f);
                plw[(quad * 4 + r) * 68 + colbit] = bf16_exact(lv);
            }
        }
        __asm__ volatile("s_waitcnt lgkmcnt(0)" ::: "memory");
        short8 Ap0 = *(const short8*)&pl[w][ci & 1][m_][quad * 8];
        short8 Ap1 = *(const short8*)&pl[w][ci & 1][m_][32 + quad * 8];
#pragma unroll
        for (int dt = 0; dt < 4; ++dt) {
            acc[dt] = __builtin_amdgcn_mfma_f32_16x16x32_bf16(Ap0, Vb0[dt], acc[dt], 0, 0, 0);
            acc[dt] = __builtin_amdgcn_mfma_f32_16x16x32_bf16(Ap1, Vb1[dt], acc[dt], 0, 0, 0);
        }
        // coalesced attn write: 4 x (b64 LDS read -> float4 store, 256B rows)
#pragma unroll
        for (int it = 0; it < 4; ++it) {
            int rrow = it * 4 + quad, col = m_ * 4;
            uint2 pk = *(const uint2*)&pl[w][ci & 1][rrow][col];
            float4 av;
            av.x = bf16_to_f((unsigned short)(pk.x & 0xffff)) * sa;
            av.y = bf16_to_f((unsigned short)(pk.x >> 16)) * sa;
            av.z = bf16_to_f((unsigned short)(pk.y & 0xffff)) * sa;
            av.w = bf16_to_f((unsigned short)(pk.y >> 16)) * sa;
            *(float4*)(attn_b + (((size_t)(rowbase + rrow)) << 10) + c * 64 + col) = av;
        }
        __asm__ volatile("s_waitcnt vmcnt(0)" ::: "memory");
        __builtin_amdgcn_s_barrier();
    }
#undef STG
    // direct out store: full 1024-col accumulation done in-register
#pragma unroll
    for (int dt = 0; dt < 4; ++dt)
#pragma unroll
        for (int r = 0; r < 4; ++r) {
            int n = rowbase + quad * 4 + r;
            int d = dt * 16 + m_;
            out[(size_t)(b * 1024 + n) * 512 + h * 64 + d] = acc[dt][r] * sa;
        }
}

// ---------------------------------------------------------------------------
extern "C" void kernel_launch(void* const* d_in, const int* in_sizes, int n_in,
                              void* d_out, int out_size, void* d_ws, size_t ws_size,
                              hipStream_t stream)
{
    (void)in_sizes; (void)n_in; (void)out_size; (void)ws_size;
    const float* x   = (const float*)d_in[0];
    const int*   adj = (const int*)d_in[1];
    const float* W_q = (const float*)d_in[2];
    const float* A_q = (const float*)d_in[3];
    const float* B_q = (const float*)d_in[4];
    const float* m_q = (const float*)d_in[5];
    const float* W_k = (const float*)d_in[6];
    const float* A_k = (const float*)d_in[7];
    const float* B_k = (const float*)d_in[8];
    const float* m_k = (const float*)d_in[9];
    const float* W_v = (const float*)d_in[10];
    const float* A_v = (const float*)d_in[11];
    const float* B_v = (const float*)d_in[12];
    const float* m_v = (const float*)d_in[13];

    char* ws = (char*)d_ws;
    unsigned short* wph = (unsigned short*)(ws + OB_WPT);            // 1.5 MB
    unsigned short* wpm = (unsigned short*)(ws + OB_WPT + 1572864);  // 1.5 MB
    unsigned short* wpl = (unsigned short*)(ws + OB_WPT + 3145728);  // 1.5 MB
    unsigned short* xh  = (unsigned short*)(ws + OB_XT);             // 8.4 MB
    unsigned short* xm  = (unsigned short*)(ws + OB_XT + 8388608);   // 8.4 MB
    unsigned short* xl  = (unsigned short*)(ws + OB_XT + 16777216);  // 8.4 MB
    float* qraw         = (float*)(ws + OB_QRAW);
    float* kraw         = (float*)(ws + OB_KRAW);
    float* vraw         = (float*)(ws + OB_VRAW);
    unsigned short* qlv = (unsigned short*)(ws + OB_QLV);   // overlays vraw
    unsigned short* klv = (unsigned short*)(ws + OB_KLV);   // overlays vraw
    unsigned short* vt  = (unsigned short*)(ws + OB_VT);    // overlays xh
    float2* rowstats    = (float2*)(ws + OB_RS);
    float2* psums       = (float2*)(ws + OB_PS);            // overlays qraw
    unsigned long long* bmask = (unsigned long long*)(ws + OB_BM);
    unsigned int* amax  = (unsigned int*)(ws + OB_AMAX);

    float* out_base  = (float*)d_out;          // (b, n, 512)
    float* attn_base = out_base + 4194304;     // (b, h, n, m)

    hipMemsetAsync(amax, 0, 16, stream);

    adj_bits_k<<<32768, 256, 0, stream>>>(adj, bmask);
    splitx_k<<<4096, 256, 0, stream>>>(x, xh, xm, xl);

    build_wp3_k<<<dim3(512, 3), 256, 0, stream>>>(W_q, A_q, B_q, m_q,
                                                  W_k, A_k, B_k, m_k,
                                                  W_v, A_v, B_v, m_v, wph, wpm, wpl);
    proj_mfma_k<<<dim3(64, 12), 512, 0, stream>>>(xh, xm, xl, wph, wpm, wpl,
                                                  qraw, kraw, vraw, amax);
    // vtrans BEFORE quant2: qlv/klv overlay vraw, which dies here
    vtrans_k<<<dim3(16, 64), 256, 0, stream>>>(vraw, vt);
    quant2_k<<<dim3(4096, 2), 256, 0, stream>>>(qraw, kraw, amax, qlv, klv);

    attn_stats_k<<<dim3(16, 64, 4), 256, 0, stream>>>(qlv, klv, bmask, amax, psums);
    stats_merge_k<<<256, 256, 0, stream>>>(psums, rowstats, amax + 2);
    attn_out_k<<<dim3(16, 64), 256, 0, stream>>>(qlv, klv, vt, bmask, amax,
                                                 rowstats, attn_base, out_base);
}

// Round 8
// 524.817 us; speedup vs baseline: 1.0330x; 1.0330x over previous
//
#include <hip/hip_runtime.h>
#include <math.h>

// Problem constants: B=8, N=1024, FIN=FOUT=512, H=8, HD=64, BH=64

typedef __attribute__((ext_vector_type(8))) short short8;    // 8 bf16 (4 VGPRs)
typedef __attribute__((ext_vector_type(4))) float floatx4;   // MFMA C/D

// Workspace byte offsets (~89 MB).
// Timeline: wph/wpm/wpl: build_wp3 -> proj. xh/xm/xl: splitx -> proj.
//   QLV overlays XH (quant2 writes after proj; xh dead).
//   VT sits in old vraw-lo (proj epilogue writes it; attn_out reads).
//   KLV in vraw-hi (quant2 -> attn). PS overlays QRAW (dead after quant2).
#define OB_WPT   0ull           // 4718592   wph/wpm/wpl bf16 planes [o=1536][k=512]
#define OB_XT    4718592ull     // 25165824  xh/xm/xl bf16 planes [t=8192][k=512]
#define OB_QLV   OB_XT          // 8388608   q levels bf16 (overlay xh, after proj)
#define OB_QRAW  36700160ull    // 16777216  q raw fp32 (b,h,n,d)
#define OB_PS    OB_QRAW        // 2097152   partial (m,l) x4 (overlay)
#define OB_KRAW  53477376ull    // 16777216  k raw fp32
#define OB_VT    70254592ull    // 8388608   v^T bf16 SWIZZLED (proj-written)
#define OB_KLV   78643200ull    // 8388608   k levels bf16 SWIZZLED
#define OB_RS    87031808ull    // 524288    rowstats float2
#define OB_BM    87556096ull    // 1048576   adj bitmask u64
#define OB_AMAX  88604672ull    // 16        amax_q, amax_k, amax_attn

__device__ __forceinline__ unsigned short bf16_rne(float f) {
    unsigned int u = __float_as_uint(f);
    unsigned int r = u + 0x7fffu + ((u >> 16) & 1u);
    return (unsigned short)(r >> 16);
}
__device__ __forceinline__ float bf16_to_f(unsigned short h) {
    return __uint_as_float(((unsigned int)h) << 16);
}
// exact for values already representable in bf16 (integer levels |x|<=127)
__device__ __forceinline__ unsigned short bf16_exact(float f) {
    return (unsigned short)(__float_as_uint(f) >> 16);
}

// async global->LDS, 16 B per lane; gptr is per-lane, LDS dest = base+lane*16
__device__ __forceinline__ void dma16u(const unsigned short* g, unsigned short* l) {
    __builtin_amdgcn_global_load_lds(
        (__attribute__((address_space(1))) void*)(void*)g,
        (__attribute__((address_space(3))) void*)(void*)l, 16, 0, 0);
}

// ---------------------------------------------------------------------------
// K0: adjacency (8,1024,1024) i32 -> bitmask (8,1024,16) u64. One word/wave.
// ---------------------------------------------------------------------------
__global__ __launch_bounds__(256) void adj_bits_k(
    const int* __restrict__ adj, unsigned long long* __restrict__ bm)
{
    int tid = threadIdx.x;
    int wv = tid >> 6, lane = tid & 63;
    size_t word = (size_t)blockIdx.x * 4 + wv;       // 131072 words total
    int a = adj[word * 64 + lane];
    unsigned long long m = __ballot(a != 0);
    if (lane == 0) bm[word] = m;
}

// ---------------------------------------------------------------------------
// K0b: x fp32 [8192][512] -> hi/mid/lo bf16 planes (cascaded rne splits).
// ---------------------------------------------------------------------------
__global__ __launch_bounds__(256) void splitx_k(
    const float* __restrict__ x, unsigned short* __restrict__ xh,
    unsigned short* __restrict__ xm, unsigned short* __restrict__ xl)
{
    int i = blockIdx.x * 256 + threadIdx.x;          // 1048576 float4s
    float4 v = ((const float4*)x)[i];
    ushort4 h, m, l;
    float r1, r2;
    h.x = bf16_rne(v.x); r1 = v.x - bf16_to_f(h.x);
    m.x = bf16_rne(r1);  r2 = r1 - bf16_to_f(m.x);  l.x = bf16_rne(r2);
    h.y = bf16_rne(v.y); r1 = v.y - bf16_to_f(h.y);
    m.y = bf16_rne(r1);  r2 = r1 - bf16_to_f(m.y);  l.y = bf16_rne(r2);
    h.z = bf16_rne(v.z); r1 = v.z - bf16_to_f(h.z);
    m.z = bf16_rne(r1);  r2 = r1 - bf16_to_f(m.z);  l.z = bf16_rne(r2);
    h.w = bf16_rne(v.w); r1 = v.w - bf16_to_f(h.w);
    m.w = bf16_rne(r1);  r2 = r1 - bf16_to_f(m.w);  l.w = bf16_rne(r2);
    ((ushort4*)xh)[i] = h;
    ((ushort4*)xm)[i] = m;
    ((ushort4*)xl)[i] = l;
}

// ---------------------------------------------------------------------------
// K1: all three DoRA-merged weights -> hi/mid/lo bf16 planes wp{h,m,l}[o][k].
// ---------------------------------------------------------------------------
__global__ __launch_bounds__(256) void build_wp3_k(
    const float* __restrict__ W_q, const float* __restrict__ A_q,
    const float* __restrict__ B_q, const float* __restrict__ m_q,
    const float* __restrict__ W_k, const float* __restrict__ A_k,
    const float* __restrict__ B_k, const float* __restrict__ m_k,
    const float* __restrict__ W_v, const float* __restrict__ A_v,
    const float* __restrict__ B_v, const float* __restrict__ m_v,
    unsigned short* __restrict__ wph, unsigned short* __restrict__ wpm,
    unsigned short* __restrict__ wpl)
{
    __shared__ float brow[16];
    __shared__ __align__(16) float wd[512];
    __shared__ float red[5];
    int o = blockIdx.x;
    int mtx = blockIdx.y;
    const float* W   = mtx == 0 ? W_q : (mtx == 1 ? W_k : W_v);
    const float* A   = mtx == 0 ? A_q : (mtx == 1 ? A_k : A_v);
    const float* Bm  = mtx == 0 ? B_q : (mtx == 1 ? B_k : B_v);
    const float* mag = mtx == 0 ? m_q : (mtx == 1 ? m_k : m_v);
    int ocol = mtx * 512 + o;
    int tid = threadIdx.x;
    if (tid < 16) brow[tid] = Bm[o * 16 + tid];
    __syncthreads();
    float ss = 0.f;
    for (int i = tid; i < 512; i += 256) {
        float acc = W[o * 512 + i];
#pragma unroll
        for (int r = 0; r < 16; ++r) acc = fmaf(brow[r], A[r * 512 + i], acc);
        wd[i] = acc;
        ss = fmaf(acc, acc, ss);
    }
#pragma unroll
    for (int off = 32; off > 0; off >>= 1) ss += __shfl_down(ss, off);
    int lane = tid & 63, wv = tid >> 6;
    if (lane == 0) red[wv] = ss;
    __syncthreads();
    if (tid == 0) red[4] = mag[o] / sqrtf(red[0] + red[1] + red[2] + red[3]);
    __syncthreads();
    float scl = red[4];
    for (int i = tid; i < 512; i += 256) {
        float v = wd[i] * scl;
        unsigned short h = bf16_rne(v);
        float r1 = v - bf16_to_f(h);
        unsigned short m = bf16_rne(r1);
        float r2 = r1 - bf16_to_f(m);
        wph[(size_t)ocol * 512 + i] = h;
        wpm[(size_t)ocol * 512 + i] = m;
        wpl[(size_t)ocol * 512 + i] = bf16_rne(r2);
    }
}

// ---------------------------------------------------------------------------
// K2: triple-split bf16 MFMA projection — round-6 measured-best geometry
// (256 threads, single-buffered 48 KB LDS -> 3 blocks/CU; cross-block TLP
// hides staging; r5/r7 double-buffer variants both regressed).
// NEW: v tiles (mtx==2) write TRANSPOSED SWIZZLED bf16 v^T directly in the
// epilogue (same bf16_rne as the old vtrans_k -> bit-identical), eliminating
// vraw and the vtrans kernel. q/k path unchanged (bit-identical).
// ---------------------------------------------------------------------------
__global__ __launch_bounds__(256) void proj_mfma_k(
    const unsigned short* __restrict__ xh, const unsigned short* __restrict__ xm,
    const unsigned short* __restrict__ xl,
    const unsigned short* __restrict__ wph, const unsigned short* __restrict__ wpm,
    const unsigned short* __restrict__ wpl,
    float* __restrict__ qraw, float* __restrict__ kraw,
    unsigned short* __restrict__ vt, unsigned int* __restrict__ amax)
{
    __shared__ __align__(16) unsigned short Ah[128][32];
    __shared__ __align__(16) unsigned short Am[128][32];
    __shared__ __align__(16) unsigned short Al[128][32];
    __shared__ __align__(16) unsigned short Bh[128][32];
    __shared__ __align__(16) unsigned short Bmd[128][32];
    __shared__ __align__(16) unsigned short Bl[128][32];
    __shared__ float redmax[4];
    int tid = threadIdx.x;
    int lane = tid & 63, w = tid >> 6;
    // XCD-chunked remap (bijective on [0,768))
    int g = blockIdx.y * 64 + blockIdx.x;
    int xcd = g & 7, slot = g >> 3;            // slot in [0,96)
    int tt = (xcd << 3) | (slot / 12);         // t-tile 0..63
    int oo = slot - (slot / 12) * 12;          // o-tile 0..11
    int t0 = tt * 128;
    int o0 = oo * 128;
    int mtx = o0 >> 9;                         // 0=q 1=k 2=v (128 | 512)
    int wt0 = (w >> 1) * 64;                   // wave's t sub-tile
    int wo0 = (w & 1) * 64;                    // wave's o sub-tile

    floatx4 acc[4][4];
#pragma unroll
    for (int mi = 0; mi < 4; ++mi)
#pragma unroll
        for (int nj = 0; nj < 4; ++nj) acc[mi][nj] = (floatx4){0.f, 0.f, 0.f, 0.f};

    int srow = w * 32 + (lane >> 2);
    int scol = (lane & 3) * 8;
    const unsigned short* gAh = xh  + (size_t)(t0 + srow) * 512 + scol;
    const unsigned short* gAm = xm  + (size_t)(t0 + srow) * 512 + scol;
    const unsigned short* gAl = xl  + (size_t)(t0 + srow) * 512 + scol;
    const unsigned short* gBh = wph + (size_t)(o0 + srow) * 512 + scol;
    const unsigned short* gBm = wpm + (size_t)(o0 + srow) * 512 + scol;
    const unsigned short* gBl = wpl + (size_t)(o0 + srow) * 512 + scol;

    int fr = lane & 15;                        // fragment row/col index
    int fk = (lane >> 4) * 8;                  // fragment k offset

    for (int kt = 0; kt < 16; ++kt) {
        size_t ko = (size_t)kt * 32;
        dma16u(gAh + ko,            &Ah[w * 32][0]);
        dma16u(gAh + ko + 16 * 512, &Ah[w * 32 + 16][0]);
        dma16u(gAm + ko,            &Am[w * 32][0]);
        dma16u(gAm + ko + 16 * 512, &Am[w * 32 + 16][0]);
        dma16u(gAl + ko,            &Al[w * 32][0]);
        dma16u(gAl + ko + 16 * 512, &Al[w * 32 + 16][0]);
        dma16u(gBh + ko,            &Bh[w * 32][0]);
        dma16u(gBh + ko + 16 * 512, &Bh[w * 32 + 16][0]);
        dma16u(gBm + ko,            &Bmd[w * 32][0]);
        dma16u(gBm + ko + 16 * 512, &Bmd[w * 32 + 16][0]);
        dma16u(gBl + ko,            &Bl[w * 32][0]);
        dma16u(gBl + ko + 16 * 512, &Bl[w * 32 + 16][0]);
        __syncthreads();

        short8 ah[4], am[4], al[4];
#pragma unroll
        for (int mi = 0; mi < 4; ++mi) {
            int ar = wt0 + mi * 16 + fr;
            ah[mi] = *(const short8*)&Ah[ar][fk];
            am[mi] = *(const short8*)&Am[ar][fk];
            al[mi] = *(const short8*)&Al[ar][fk];
        }
#pragma unroll
        for (int nj = 0; nj < 4; ++nj) {
            int br = wo0 + nj * 16 + fr;
            short8 bh = *(const short8*)&Bh[br][fk];
            short8 bm = *(const short8*)&Bmd[br][fk];
            short8 bl = *(const short8*)&Bl[br][fk];
#pragma unroll
            for (int mi = 0; mi < 4; ++mi) {
                acc[mi][nj] = __builtin_amdgcn_mfma_f32_16x16x32_bf16(ah[mi], bh, acc[mi][nj], 0, 0, 0);
                acc[mi][nj] = __builtin_amdgcn_mfma_f32_16x16x32_bf16(ah[mi], bm, acc[mi][nj], 0, 0, 0);
                acc[mi][nj] = __builtin_amdgcn_mfma_f32_16x16x32_bf16(am[mi], bh, acc[mi][nj], 0, 0, 0);
                acc[mi][nj] = __builtin_amdgcn_mfma_f32_16x16x32_bf16(ah[mi], bl, acc[mi][nj], 0, 0, 0);
                acc[mi][nj] = __builtin_amdgcn_mfma_f32_16x16x32_bf16(al[mi], bh, acc[mi][nj], 0, 0, 0);
                acc[mi][nj] = __builtin_amdgcn_mfma_f32_16x16x32_bf16(am[mi], bm, acc[mi][nj], 0, 0, 0);
            }
        }
        __syncthreads();
    }

    if (mtx < 2) {
        // q/k epilogue: fp32 raw scatter + amax (bit-identical to r6)
        float* dst = mtx == 0 ? qraw : kraw;
        float mx = 0.f;
#pragma unroll
        for (int mi = 0; mi < 4; ++mi) {
#pragma unroll
            for (int r = 0; r < 4; ++r) {
                int t = t0 + wt0 + mi * 16 + (lane >> 4) * 4 + r;
                int b = t >> 10, n = t & 1023;
#pragma unroll
                for (int nj = 0; nj < 4; ++nj) {
                    int o = o0 + wo0 + nj * 16 + fr;
                    int h = (o >> 6) & 7, d = o & 63;
                    float val = acc[mi][nj][r];
                    dst[((size_t)(b * 8 + h) * 1024 + n) * 64 + d] = val;
                    mx = fmaxf(mx, fabsf(val));
                }
            }
        }
#pragma unroll
        for (int off = 32; off > 0; off >>= 1) mx = fmaxf(mx, __shfl_down(mx, off));
        if ((tid & 63) == 0) redmax[tid >> 6] = mx;
        __syncthreads();
        if (tid == 0) {
            float m2 = fmaxf(fmaxf(redmax[0], redmax[1]), fmaxf(redmax[2], redmax[3]));
            atomicMax(&amax[mtx], __float_as_uint(m2));
        }
    } else {
        // v epilogue: direct transposed+swizzled bf16 v^T (replaces vtrans_k).
        // n0 is 4-aligned and 16-block-aligned base -> ml>>3 constant over r,
        // mlp consecutive over r -> one ushort4 per (mi,nj).
#pragma unroll
        for (int mi = 0; mi < 4; ++mi) {
            int t0r = t0 + wt0 + mi * 16 + (lane >> 4) * 4;
            int b = t0r >> 10, n0 = t0r & 1023;
            int ml = n0 & 63, mb = n0 - ml;
#pragma unroll
            for (int nj = 0; nj < 4; ++nj) {
                int o = o0 + wo0 + nj * 16 + fr;
                int h = (o >> 6) & 7, d = o & 63;
                int mlp = (ml & 7) | ((((ml >> 3) ^ d) & 7) << 3);
                ushort4 hv;
                hv.x = bf16_rne(acc[mi][nj][0]);
                hv.y = bf16_rne(acc[mi][nj][1]);
                hv.z = bf16_rne(acc[mi][nj][2]);
                hv.w = bf16_rne(acc[mi][nj][3]);
                *(ushort4*)(vt + ((size_t)((b * 8 + h) * 64 + d)) * 1024 + mb + mlp) = hv;
            }
        }
    }
}

// ---------------------------------------------------------------------------
// K2b: q AND k raw fp32 -> int8 levels as exact bf16 (grid.y=2).
// q written LINEAR; k written XOR-SWIZZLED within each 128 B row
// (chunk16 ^= n&7) so attn kernels can DMA-stage linearly and ds_read
// bank-conflict-free (T2 both-sides rule).
// ---------------------------------------------------------------------------
__global__ __launch_bounds__(256) void quant2_k(
    const float* __restrict__ qraw, const float* __restrict__ kraw,
    const unsigned int* __restrict__ amax,
    unsigned short* __restrict__ qlv, unsigned short* __restrict__ klv)
{
    int m = blockIdx.y;
    const float* raw = m ? kraw : qraw;
    unsigned short* lv = m ? klv : qlv;
    float scale = fmaxf(__uint_as_float(amax[m]) / 127.f, 1e-8f);
    int i = blockIdx.x * 256 + threadIdx.x;          // n4 = 1048576
    float4 v = ((const float4*)raw)[i];
    float l0 = fminf(fmaxf(rintf(v.x / scale), -127.f), 127.f);
    float l1 = fminf(fmaxf(rintf(v.y / scale), -127.f), 127.f);
    float l2 = fminf(fmaxf(rintf(v.z / scale), -127.f), 127.f);
    float l3 = fminf(fmaxf(rintf(v.w / scale), -127.f), 127.f);
    ushort4 o;
    o.x = bf16_exact(l0); o.y = bf16_exact(l1);
    o.z = bf16_exact(l2); o.w = bf16_exact(l3);
    int idx4 = i;
    if (m) {
        int elem0 = i * 4;
        int d0 = elem0 & 63;
        int n = (elem0 >> 6) & 1023;
        int dp = (d0 & 7) | ((((d0 >> 3) ^ n) & 7) << 3);
        idx4 = (elem0 - d0 + dp) >> 2;
    }
    ((ushort4*)lv)[idx4] = o;
}

// ---------------------------------------------------------------------------
// K3a: MFMA scores + bitmask + online (m,l) over a column QUARTER.
// K tiles STAGED in LDS (double-buffered, linear DMA of the pre-swizzled
// klv) shared by all 4 waves -> 4x fewer global K reads; swizzled ds_read
// is bank-conflict-free. Grid (16 qt, 64 bh, 4 quarter), XCD-chunked remap.
// ---------------------------------------------------------------------------
__global__ __launch_bounds__(256) void attn_stats_k(
    const unsigned short* __restrict__ qlv, const unsigned short* __restrict__ klv,
    const unsigned long long* __restrict__ bm, const unsigned int* __restrict__ amax,
    float2* __restrict__ psums)
{
    __shared__ __align__(16) unsigned short Ks[2][64][64];   // 16 KB dbuf
    int tid = threadIdx.x;
    int lane = tid & 63, w = tid >> 6;
    int m_ = lane & 15, quad = lane >> 4;
    // remap (bijective on [0,4096))
    int g = blockIdx.z * 1024 + blockIdx.y * 16 + blockIdx.x;
    int xcd = g & 7, slot = g >> 3;            // slot in [0,512)
    int bh = (xcd << 3) | (slot >> 6);
    int rem = slot & 63;
    int qt = rem >> 2, qtr = rem & 3;
    int b = bh >> 3;
    int rowbase = qt * 64 + w * 16;
    float sq = fmaxf(__uint_as_float(amax[0]) / 127.f, 1e-8f);
    float sk = fmaxf(__uint_as_float(amax[1]) / 127.f, 1e-8f);
    float ss = sq * sk;

    const unsigned short* qp = qlv + ((size_t)bh * 1024 + rowbase + m_) * 64;
    short8 Aq0 = *(const short8*)(qp + quad * 8);
    short8 Aq1 = *(const short8*)(qp + 32 + quad * 8);
    const unsigned long long* bmb = bm + ((size_t)b * 1024 + rowbase) * 16;

    // staging: wave w stages tile rows [w*16, w*16+16); lane l -> row l>>3,
    // 16B chunk l&7 (linear, matches LDS dest base+lane*16)
    const unsigned short* gK = klv + ((size_t)bh * 1024 + w * 16) * 64 + lane * 8;
    int sw0 = ((quad ^ m_) & 7) << 3;          // B0 swizzled col (row parity m_&7)
    int sw1 = (((4 + quad) ^ m_) & 7) << 3;    // B1

    float mrun[4], lrun[4];
#pragma unroll
    for (int r = 0; r < 4; ++r) { mrun[r] = -1e9f; lrun[r] = 0.f; }

    {
        size_t off = (size_t)(qtr * 4) * 4096;
        dma16u(gK + off,       &Ks[0][w * 16][0]);
        dma16u(gK + off + 512, &Ks[0][w * 16 + 8][0]);
    }
    __asm__ volatile("s_waitcnt vmcnt(0)" ::: "memory");
    __builtin_amdgcn_s_barrier();

    for (int ci = 0; ci < 4; ++ci) {
        int c = qtr * 4 + ci;
        int buf = ci & 1;
        if (ci < 3) {
            size_t off = (size_t)(c + 1) * 4096;
            dma16u(gK + off,       &Ks[buf ^ 1][w * 16][0]);
            dma16u(gK + off + 512, &Ks[buf ^ 1][w * 16 + 8][0]);
        }
        unsigned long long mk[4];
#pragma unroll
        for (int r = 0; r < 4; ++r) mk[r] = bmb[(quad * 4 + r) * 16 + c];
        float sv[4][4];
#pragma unroll
        for (int s = 0; s < 4; ++s) {
            short8 B0 = *(const short8*)&Ks[buf][s * 16 + m_][sw0];
            short8 B1 = *(const short8*)&Ks[buf][s * 16 + m_][sw1];
            floatx4 Cv = {0.f, 0.f, 0.f, 0.f};
            Cv = __builtin_amdgcn_mfma_f32_16x16x32_bf16(Aq0, B0, Cv, 0, 0, 0);
            Cv = __builtin_amdgcn_mfma_f32_16x16x32_bf16(Aq1, B1, Cv, 0, 0, 0);
            int colbit = s * 16 + m_;
#pragma unroll
            for (int r = 0; r < 4; ++r)
                sv[r][s] = ((mk[r] >> colbit) & 1ull) ? Cv[r] * ss : -1e9f;
        }
#pragma unroll
        for (int r = 0; r < 4; ++r) {
            float tm = fmaxf(fmaxf(sv[r][0], sv[r][1]), fmaxf(sv[r][2], sv[r][3]));
            float mn = fmaxf(mrun[r], tm);
            float e = __expf(sv[r][0] - mn) + __expf(sv[r][1] - mn)
                    + __expf(sv[r][2] - mn) + __expf(sv[r][3] - mn);
            lrun[r] = fmaf(lrun[r], __expf(mrun[r] - mn), e);
            mrun[r] = mn;
        }
        __asm__ volatile("s_waitcnt vmcnt(0)" ::: "memory");
        __builtin_amdgcn_s_barrier();
    }

#pragma unroll
    for (int r = 0; r < 4; ++r) {
        float m = mrun[r], l = lrun[r];
#pragma unroll
        for (int off = 1; off < 16; off <<= 1) {
            float mo = __shfl_xor(m, off);
            float lo = __shfl_xor(l, off);
            float mn = fmaxf(m, mo);
            l = l * __expf(m - mn) + lo * __expf(mo - mn);
            m = mn;
        }
        if (m_ == 0)
            psums[(size_t)qtr * 65536 + (size_t)bh * 1024 + rowbase + quad * 4 + r] =
                make_float2(m, l);
    }
}

// ---------------------------------------------------------------------------
// K3a2: merge 4 quarter-(m,l) into rowstats; global attn amax = max 1/l.
// ---------------------------------------------------------------------------
__global__ __launch_bounds__(256) void stats_merge_k(
    const float2* __restrict__ ps, float2* __restrict__ rowstats,
    unsigned int* __restrict__ amax_attn)
{
    int row = blockIdx.x * 256 + threadIdx.x;        // 65536 rows
    float2 a = ps[row];
    float m = a.x, l = a.y;
#pragma unroll
    for (int q = 1; q < 4; ++q) {
        float2 bq = ps[(size_t)q * 65536 + row];
        float mn = fmaxf(m, bq.x);
        l = l * __expf(m - mn) + bq.y * __expf(bq.x - mn);
        m = mn;
    }
    rowstats[row] = make_float2(m, l);
    float inv = 1.0f / l;
#pragma unroll
    for (int off = 1; off < 64; off <<= 1) inv = fmaxf(inv, __shfl_xor(inv, off));
    if ((threadIdx.x & 63) == 0) atomicMax(amax_attn, __float_as_uint(inv));
}

// ---------------------------------------------------------------------------
// K3b: full-row attn+out with K AND V tiles STAGED in LDS (double-buffered
// linear DMA of pre-swizzled klv/vt, shared by 4 waves -> 4x fewer global
// reads). Scores bit-identical; P quantize + coalesced attn writes + fused
// P@V MFMA; direct out store. XCD-chunked remap.
// LDS: Ks 16K + Vs 16K + pl 17.4K = 49.4 KB -> 3 blocks/CU.
// ---------------------------------------------------------------------------
__global__ __launch_bounds__(256) void attn_out_k(
    const unsigned short* __restrict__ qlv, const unsigned short* __restrict__ klv,
    const unsigned short* __restrict__ vt,
    const unsigned long long* __restrict__ bm, const unsigned int* __restrict__ amax,
    const float2* __restrict__ rowstats,
    float* __restrict__ attn, float* __restrict__ out)
{
    __shared__ __align__(16) unsigned short Ks[2][64][64];   // 16 KB
    __shared__ __align__(16) unsigned short Vs[2][64][64];   // 16 KB
    __shared__ unsigned short pl[4][2][16][68];              // per-wave P dbuf
    int tid = threadIdx.x;
    int lane = tid & 63, w = tid >> 6;
    int m_ = lane & 15, quad = lane >> 4;
    // remap (bijective on [0,1024))
    int g = blockIdx.y * 16 + blockIdx.x;
    int xcd = g & 7, slot = g >> 3;            // slot in [0,128)
    int bh = (xcd << 3) | (slot >> 4);
    int qt = slot & 15;
    int b = bh >> 3, h = bh & 7;
    int rowbase = qt * 64 + w * 16;
    float sq = fmaxf(__uint_as_float(amax[0]) / 127.f, 1e-8f);
    float sk = fmaxf(__uint_as_float(amax[1]) / 127.f, 1e-8f);
    float ss = sq * sk;
    float sa = fmaxf(__uint_as_float(amax[2]) / 127.f, 1e-8f);
    float inv_sa = 1.0f / sa;

    const unsigned short* qp = qlv + ((size_t)bh * 1024 + rowbase + m_) * 64;
    short8 Aq0 = *(const short8*)(qp + quad * 8);
    short8 Aq1 = *(const short8*)(qp + 32 + quad * 8);
    const unsigned long long* bmb = bm + ((size_t)b * 1024 + rowbase) * 16;

    // staging pointers: wave w stages tile rows [w*16, w*16+16)
    const unsigned short* gK  = klv + ((size_t)bh * 1024 + w * 16) * 64 + lane * 8;
    const unsigned short* gV  = vt + ((size_t)(bh * 64 + w * 16 + (lane >> 3))) * 1024 + (lane & 7) * 8;
    const unsigned short* gV2 = gV + 8 * 1024;
    int sw0 = ((quad ^ m_) & 7) << 3;
    int sw1 = (((4 + quad) ^ m_) & 7) << 3;

    float mrow[4], rlr[4];
#pragma unroll
    for (int r = 0; r < 4; ++r) {
        float2 st = rowstats[(size_t)bh * 1024 + rowbase + quad * 4 + r];
        mrow[r] = st.x;
        rlr[r] = 1.0f / st.y;
    }
    floatx4 acc[4];
#pragma unroll
    for (int r = 0; r < 4; ++r) acc[r] = (floatx4){0.f, 0.f, 0.f, 0.f};

    float* attn_b = attn + ((size_t)bh << 20);

#define STG(bf, cc) do {                                                  \
        dma16u(gK + (size_t)(cc) * 4096,       &Ks[bf][w * 16][0]);       \
        dma16u(gK + (size_t)(cc) * 4096 + 512, &Ks[bf][w * 16 + 8][0]);   \
        dma16u(gV + (cc) * 64,                 &Vs[bf][w * 16][0]);       \
        dma16u(gV2 + (cc) * 64,                &Vs[bf][w * 16 + 8][0]);   \
    } while (0)

    STG(0, 0);
    __asm__ volatile("s_waitcnt vmcnt(0)" ::: "memory");
    __builtin_amdgcn_s_barrier();

    for (int ci = 0; ci < 16; ++ci) {
        int c = ci;
        int buf = ci & 1;
        if (ci + 1 < 16) STG(buf ^ 1, ci + 1);
        // V fragments from LDS (buf ready via prior barrier)
        short8 Vb0[4], Vb1[4];
#pragma unroll
        for (int dt = 0; dt < 4; ++dt) {
            Vb0[dt] = *(const short8*)&Vs[buf][dt * 16 + m_][sw0];
            Vb1[dt] = *(const short8*)&Vs[buf][dt * 16 + m_][sw1];
        }
        unsigned long long mk[4];
#pragma unroll
        for (int r = 0; r < 4; ++r) mk[r] = bmb[(quad * 4 + r) * 16 + c];
        unsigned short* plw = &pl[w][ci & 1][0][0];
#pragma unroll
        for (int s = 0; s < 4; ++s) {
            short8 B0 = *(const short8*)&Ks[buf][s * 16 + m_][sw0];
            short8 B1 = *(const short8*)&Ks[buf][s * 16 + m_][sw1];
            floatx4 Cv = {0.f, 0.f, 0.f, 0.f};
            Cv = __builtin_amdgcn_mfma_f32_16x16x32_bf16(Aq0, B0, Cv, 0, 0, 0);
            Cv = __builtin_amdgcn_mfma_f32_16x16x32_bf16(Aq1, B1, Cv, 0, 0, 0);
            int colbit = s * 16 + m_;
#pragma unroll
            for (int r = 0; r < 4; ++r) {
                float sval = ((mk[r] >> colbit) & 1ull) ? Cv[r] * ss : -1e9f;
                float p = __expf(sval - mrow[r]) * rlr[r];   // round-3 op order
                float lv = fminf(rintf(p * inv_sa), 127.f);
                plw[(quad * 4 + r) * 68 + colbit] = bf16_exact(lv);
            }
        }
        __asm__ volatile("s_waitcnt lgkmcnt(0)" ::: "memory");
        short8 Ap0 = *(const short8*)&pl[w][ci & 1][m_][quad * 8];
        short8 Ap1 = *(const short8*)&pl[w][ci & 1][m_][32 + quad * 8];
#pragma unroll
        for (int dt = 0; dt < 4; ++dt) {
            acc[dt] = __builtin_amdgcn_mfma_f32_16x16x32_bf16(Ap0, Vb0[dt], acc[dt], 0, 0, 0);
            acc[dt] = __builtin_amdgcn_mfma_f32_16x16x32_bf16(Ap1, Vb1[dt], acc[dt], 0, 0, 0);
        }
        // coalesced attn write: 4 x (b64 LDS read -> float4 store, 256B rows)
#pragma unroll
        for (int it = 0; it < 4; ++it) {
            int rrow = it * 4 + quad, col = m_ * 4;
            uint2 pk = *(const uint2*)&pl[w][ci & 1][rrow][col];
            float4 av;
            av.x = bf16_to_f((unsigned short)(pk.x & 0xffff)) * sa;
            av.y = bf16_to_f((unsigned short)(pk.x >> 16)) * sa;
            av.z = bf16_to_f((unsigned short)(pk.y & 0xffff)) * sa;
            av.w = bf16_to_f((unsigned short)(pk.y >> 16)) * sa;
            *(float4*)(attn_b + (((size_t)(rowbase + rrow)) << 10) + c * 64 + col) = av;
        }
        __asm__ volatile("s_waitcnt vmcnt(0)" ::: "memory");
        __builtin_amdgcn_s_barrier();
    }
#undef STG
    // direct out store: full 1024-col accumulation done in-register
#pragma unroll
    for (int dt = 0; dt < 4; ++dt)
#pragma unroll
        for (int r = 0; r < 4; ++r) {
            int n = rowbase + quad * 4 + r;
            int d = dt * 16 + m_;
            out[(size_t)(b * 1024 + n) * 512 + h * 64 + d] = acc[dt][r] * sa;
        }
}

// ---------------------------------------------------------------------------
extern "C" void kernel_launch(void* const* d_in, const int* in_sizes, int n_in,
                              void* d_out, int out_size, void* d_ws, size_t ws_size,
                              hipStream_t stream)
{
    (void)in_sizes; (void)n_in; (void)out_size; (void)ws_size;
    const float* x   = (const float*)d_in[0];
    const int*   adj = (const int*)d_in[1];
    const float* W_q = (const float*)d_in[2];
    const float* A_q = (const float*)d_in[3];
    const float* B_q = (const float*)d_in[4];
    const float* m_q = (const float*)d_in[5];
    const float* W_k = (const float*)d_in[6];
    const float* A_k = (const float*)d_in[7];
    const float* B_k = (const float*)d_in[8];
    const float* m_k = (const float*)d_in[9];
    const float* W_v = (const float*)d_in[10];
    const float* A_v = (const float*)d_in[11];
    const float* B_v = (const float*)d_in[12];
    const float* m_v = (const float*)d_in[13];

    char* ws = (char*)d_ws;
    unsigned short* wph = (unsigned short*)(ws + OB_WPT);            // 1.5 MB
    unsigned short* wpm = (unsigned short*)(ws + OB_WPT + 1572864);  // 1.5 MB
    unsigned short* wpl = (unsigned short*)(ws + OB_WPT + 3145728);  // 1.5 MB
    unsigned short* xh  = (unsigned short*)(ws + OB_XT);             // 8.4 MB
    unsigned short* xm  = (unsigned short*)(ws + OB_XT + 8388608);   // 8.4 MB
    unsigned short* xl  = (unsigned short*)(ws + OB_XT + 16777216);  // 8.4 MB
    float* qraw         = (float*)(ws + OB_QRAW);
    float* kraw         = (float*)(ws + OB_KRAW);
    unsigned short* qlv = (unsigned short*)(ws + OB_QLV);   // overlays xh
    unsigned short* klv = (unsigned short*)(ws + OB_KLV);
    unsigned short* vt  = (unsigned short*)(ws + OB_VT);    // proj-written
    float2* rowstats    = (float2*)(ws + OB_RS);
    float2* psums       = (float2*)(ws + OB_PS);            // overlays qraw
    unsigned long long* bmask = (unsigned long long*)(ws + OB_BM);
    unsigned int* amax  = (unsigned int*)(ws + OB_AMAX);

    float* out_base  = (float*)d_out;          // (b, n, 512)
    float* attn_base = out_base + 4194304;     // (b, h, n, m)

    hipMemsetAsync(amax, 0, 16, stream);

    adj_bits_k<<<32768, 256, 0, stream>>>(adj, bmask);
    splitx_k<<<4096, 256, 0, stream>>>(x, xh, xm, xl);

    build_wp3_k<<<dim3(512, 3), 256, 0, stream>>>(W_q, A_q, B_q, m_q,
                                                  W_k, A_k, B_k, m_k,
                                                  W_v, A_v, B_v, m_v, wph, wpm, wpl);
    proj_mfma_k<<<dim3(64, 12), 256, 0, stream>>>(xh, xm, xl, wph, wpm, wpl,
                                                  qraw, kraw, vt, amax);
    quant2_k<<<dim3(4096, 2), 256, 0, stream>>>(qraw, kraw, amax, qlv, klv);

    attn_stats_k<<<dim3(16, 64, 4), 256, 0, stream>>>(qlv, klv, bmask, amax, psums);
    stats_merge_k<<<256, 256, 0, stream>>>(psums, rowstats, amax + 2);
    attn_out_k<<<dim3(16, 64), 256, 0, stream>>>(qlv, klv, vt, bmask, amax,
                                                 rowstats, attn_base, out_base);
}

// Round 9
// 522.783 us; speedup vs baseline: 1.0370x; 1.0039x over previous
//
#include <hip/hip_runtime.h>
#include <math.h>

// Problem constants: B=8, N=1024, FIN=FOUT=512, H=8, HD=64, BH=64

typedef __attribute__((ext_vector_type(8))) short short8;    // 8 bf16 (4 VGPRs)
typedef __attribute__((ext_vector_type(4))) float floatx4;   // MFMA C/D

// Workspace byte offsets (~89 MB).
// Timeline: wph/wpm/wpl: build_wp3 -> proj. xh/xm/xl: splitx -> proj.
//   QLV overlays XH (quant2 writes after proj; xh dead).
//   VT sits in old vraw-lo (proj epilogue writes it; attn_out reads).
//   KLV in vraw-hi (quant2 -> attn).
#define OB_WPT   0ull           // 4718592   wph/wpm/wpl bf16 planes [o=1536][k=512]
#define OB_XT    4718592ull     // 25165824  xh/xm/xl bf16 planes [t=8192][k=512]
#define OB_QLV   OB_XT          // 8388608   q levels bf16 (overlay xh, after proj)
#define OB_QRAW  36700160ull    // 16777216  q raw fp32 (b,h,n,d)
#define OB_KRAW  53477376ull    // 16777216  k raw fp32
#define OB_VT    70254592ull    // 8388608   v^T bf16 SWIZZLED (proj-written)
#define OB_KLV   78643200ull    // 8388608   k levels bf16 SWIZZLED
#define OB_RS    87031808ull    // 524288    rowstats float2
#define OB_BM    87556096ull    // 1048576   adj bitmask u64
#define OB_AMAX  88604672ull    // 16        amax_q, amax_k, amax_attn

__device__ __forceinline__ unsigned short bf16_rne(float f) {
    unsigned int u = __float_as_uint(f);
    unsigned int r = u + 0x7fffu + ((u >> 16) & 1u);
    return (unsigned short)(r >> 16);
}
__device__ __forceinline__ float bf16_to_f(unsigned short h) {
    return __uint_as_float(((unsigned int)h) << 16);
}
// exact for values already representable in bf16 (integer levels |x|<=127)
__device__ __forceinline__ unsigned short bf16_exact(float f) {
    return (unsigned short)(__float_as_uint(f) >> 16);
}

// async global->LDS, 16 B per lane; gptr is per-lane, LDS dest = base+lane*16
__device__ __forceinline__ void dma16u(const unsigned short* g, unsigned short* l) {
    __builtin_amdgcn_global_load_lds(
        (__attribute__((address_space(1))) void*)(void*)g,
        (__attribute__((address_space(3))) void*)(void*)l, 16, 0, 0);
}

// ---------------------------------------------------------------------------
// K0: adjacency (8,1024,1024) i32 -> bitmask (8,1024,16) u64. One word/wave.
// ---------------------------------------------------------------------------
__global__ __launch_bounds__(256) void adj_bits_k(
    const int* __restrict__ adj, unsigned long long* __restrict__ bm)
{
    int tid = threadIdx.x;
    int wv = tid >> 6, lane = tid & 63;
    size_t word = (size_t)blockIdx.x * 4 + wv;       // 131072 words total
    int a = adj[word * 64 + lane];
    unsigned long long m = __ballot(a != 0);
    if (lane == 0) bm[word] = m;
}

// ---------------------------------------------------------------------------
// K0b: x fp32 [8192][512] -> hi/mid/lo bf16 planes (cascaded rne splits).
// ---------------------------------------------------------------------------
__global__ __launch_bounds__(256) void splitx_k(
    const float* __restrict__ x, unsigned short* __restrict__ xh,
    unsigned short* __restrict__ xm, unsigned short* __restrict__ xl)
{
    int i = blockIdx.x * 256 + threadIdx.x;          // 1048576 float4s
    float4 v = ((const float4*)x)[i];
    ushort4 h, m, l;
    float r1, r2;
    h.x = bf16_rne(v.x); r1 = v.x - bf16_to_f(h.x);
    m.x = bf16_rne(r1);  r2 = r1 - bf16_to_f(m.x);  l.x = bf16_rne(r2);
    h.y = bf16_rne(v.y); r1 = v.y - bf16_to_f(h.y);
    m.y = bf16_rne(r1);  r2 = r1 - bf16_to_f(m.y);  l.y = bf16_rne(r2);
    h.z = bf16_rne(v.z); r1 = v.z - bf16_to_f(h.z);
    m.z = bf16_rne(r1);  r2 = r1 - bf16_to_f(m.z);  l.z = bf16_rne(r2);
    h.w = bf16_rne(v.w); r1 = v.w - bf16_to_f(h.w);
    m.w = bf16_rne(r1);  r2 = r1 - bf16_to_f(m.w);  l.w = bf16_rne(r2);
    ((ushort4*)xh)[i] = h;
    ((ushort4*)xm)[i] = m;
    ((ushort4*)xl)[i] = l;
}

// ---------------------------------------------------------------------------
// K1: all three DoRA-merged weights -> hi/mid/lo bf16 planes wp{h,m,l}[o][k].
// ---------------------------------------------------------------------------
__global__ __launch_bounds__(256) void build_wp3_k(
    const float* __restrict__ W_q, const float* __restrict__ A_q,
    const float* __restrict__ B_q, const float* __restrict__ m_q,
    const float* __restrict__ W_k, const float* __restrict__ A_k,
    const float* __restrict__ B_k, const float* __restrict__ m_k,
    const float* __restrict__ W_v, const float* __restrict__ A_v,
    const float* __restrict__ B_v, const float* __restrict__ m_v,
    unsigned short* __restrict__ wph, unsigned short* __restrict__ wpm,
    unsigned short* __restrict__ wpl)
{
    __shared__ float brow[16];
    __shared__ __align__(16) float wd[512];
    __shared__ float red[5];
    int o = blockIdx.x;
    int mtx = blockIdx.y;
    const float* W   = mtx == 0 ? W_q : (mtx == 1 ? W_k : W_v);
    const float* A   = mtx == 0 ? A_q : (mtx == 1 ? A_k : A_v);
    const float* Bm  = mtx == 0 ? B_q : (mtx == 1 ? B_k : B_v);
    const float* mag = mtx == 0 ? m_q : (mtx == 1 ? m_k : m_v);
    int ocol = mtx * 512 + o;
    int tid = threadIdx.x;
    if (tid < 16) brow[tid] = Bm[o * 16 + tid];
    __syncthreads();
    float ss = 0.f;
    for (int i = tid; i < 512; i += 256) {
        float acc = W[o * 512 + i];
#pragma unroll
        for (int r = 0; r < 16; ++r) acc = fmaf(brow[r], A[r * 512 + i], acc);
        wd[i] = acc;
        ss = fmaf(acc, acc, ss);
    }
#pragma unroll
    for (int off = 32; off > 0; off >>= 1) ss += __shfl_down(ss, off);
    int lane = tid & 63, wv = tid >> 6;
    if (lane == 0) red[wv] = ss;
    __syncthreads();
    if (tid == 0) red[4] = mag[o] / sqrtf(red[0] + red[1] + red[2] + red[3]);
    __syncthreads();
    float scl = red[4];
    for (int i = tid; i < 512; i += 256) {
        float v = wd[i] * scl;
        unsigned short h = bf16_rne(v);
        float r1 = v - bf16_to_f(h);
        unsigned short m = bf16_rne(r1);
        float r2 = r1 - bf16_to_f(m);
        wph[(size_t)ocol * 512 + i] = h;
        wpm[(size_t)ocol * 512 + i] = m;
        wpl[(size_t)ocol * 512 + i] = bf16_rne(r2);
    }
}

// ---------------------------------------------------------------------------
// K2: triple-split bf16 MFMA projection — round-6 measured-best geometry
// (256 threads, single-buffered 48 KB LDS -> 3 blocks/CU; cross-block TLP
// hides staging; r5/r7 double-buffer variants both regressed).
// v tiles (mtx==2) write TRANSPOSED SWIZZLED bf16 v^T directly in the
// epilogue (same bf16_rne as old vtrans_k -> bit-identical).
// ---------------------------------------------------------------------------
__global__ __launch_bounds__(256) void proj_mfma_k(
    const unsigned short* __restrict__ xh, const unsigned short* __restrict__ xm,
    const unsigned short* __restrict__ xl,
    const unsigned short* __restrict__ wph, const unsigned short* __restrict__ wpm,
    const unsigned short* __restrict__ wpl,
    float* __restrict__ qraw, float* __restrict__ kraw,
    unsigned short* __restrict__ vt, unsigned int* __restrict__ amax)
{
    __shared__ __align__(16) unsigned short Ah[128][32];
    __shared__ __align__(16) unsigned short Am[128][32];
    __shared__ __align__(16) unsigned short Al[128][32];
    __shared__ __align__(16) unsigned short Bh[128][32];
    __shared__ __align__(16) unsigned short Bmd[128][32];
    __shared__ __align__(16) unsigned short Bl[128][32];
    __shared__ float redmax[4];
    int tid = threadIdx.x;
    int lane = tid & 63, w = tid >> 6;
    // XCD-chunked remap (bijective on [0,768))
    int g = blockIdx.y * 64 + blockIdx.x;
    int xcd = g & 7, slot = g >> 3;            // slot in [0,96)
    int tt = (xcd << 3) | (slot / 12);         // t-tile 0..63
    int oo = slot - (slot / 12) * 12;          // o-tile 0..11
    int t0 = tt * 128;
    int o0 = oo * 128;
    int mtx = o0 >> 9;                         // 0=q 1=k 2=v (128 | 512)
    int wt0 = (w >> 1) * 64;                   // wave's t sub-tile
    int wo0 = (w & 1) * 64;                    // wave's o sub-tile

    floatx4 acc[4][4];
#pragma unroll
    for (int mi = 0; mi < 4; ++mi)
#pragma unroll
        for (int nj = 0; nj < 4; ++nj) acc[mi][nj] = (floatx4){0.f, 0.f, 0.f, 0.f};

    int srow = w * 32 + (lane >> 2);
    int scol = (lane & 3) * 8;
    const unsigned short* gAh = xh  + (size_t)(t0 + srow) * 512 + scol;
    const unsigned short* gAm = xm  + (size_t)(t0 + srow) * 512 + scol;
    const unsigned short* gAl = xl  + (size_t)(t0 + srow) * 512 + scol;
    const unsigned short* gBh = wph + (size_t)(o0 + srow) * 512 + scol;
    const unsigned short* gBm = wpm + (size_t)(o0 + srow) * 512 + scol;
    const unsigned short* gBl = wpl + (size_t)(o0 + srow) * 512 + scol;

    int fr = lane & 15;                        // fragment row/col index
    int fk = (lane >> 4) * 8;                  // fragment k offset

    for (int kt = 0; kt < 16; ++kt) {
        size_t ko = (size_t)kt * 32;
        dma16u(gAh + ko,            &Ah[w * 32][0]);
        dma16u(gAh + ko + 16 * 512, &Ah[w * 32 + 16][0]);
        dma16u(gAm + ko,            &Am[w * 32][0]);
        dma16u(gAm + ko + 16 * 512, &Am[w * 32 + 16][0]);
        dma16u(gAl + ko,            &Al[w * 32][0]);
        dma16u(gAl + ko + 16 * 512, &Al[w * 32 + 16][0]);
        dma16u(gBh + ko,            &Bh[w * 32][0]);
        dma16u(gBh + ko + 16 * 512, &Bh[w * 32 + 16][0]);
        dma16u(gBm + ko,            &Bmd[w * 32][0]);
        dma16u(gBm + ko + 16 * 512, &Bmd[w * 32 + 16][0]);
        dma16u(gBl + ko,            &Bl[w * 32][0]);
        dma16u(gBl + ko + 16 * 512, &Bl[w * 32 + 16][0]);
        __syncthreads();

        short8 ah[4], am[4], al[4];
#pragma unroll
        for (int mi = 0; mi < 4; ++mi) {
            int ar = wt0 + mi * 16 + fr;
            ah[mi] = *(const short8*)&Ah[ar][fk];
            am[mi] = *(const short8*)&Am[ar][fk];
            al[mi] = *(const short8*)&Al[ar][fk];
        }
#pragma unroll
        for (int nj = 0; nj < 4; ++nj) {
            int br = wo0 + nj * 16 + fr;
            short8 bh = *(const short8*)&Bh[br][fk];
            short8 bm = *(const short8*)&Bmd[br][fk];
            short8 bl = *(const short8*)&Bl[br][fk];
#pragma unroll
            for (int mi = 0; mi < 4; ++mi) {
                acc[mi][nj] = __builtin_amdgcn_mfma_f32_16x16x32_bf16(ah[mi], bh, acc[mi][nj], 0, 0, 0);
                acc[mi][nj] = __builtin_amdgcn_mfma_f32_16x16x32_bf16(ah[mi], bm, acc[mi][nj], 0, 0, 0);
                acc[mi][nj] = __builtin_amdgcn_mfma_f32_16x16x32_bf16(am[mi], bh, acc[mi][nj], 0, 0, 0);
                acc[mi][nj] = __builtin_amdgcn_mfma_f32_16x16x32_bf16(ah[mi], bl, acc[mi][nj], 0, 0, 0);
                acc[mi][nj] = __builtin_amdgcn_mfma_f32_16x16x32_bf16(al[mi], bh, acc[mi][nj], 0, 0, 0);
                acc[mi][nj] = __builtin_amdgcn_mfma_f32_16x16x32_bf16(am[mi], bm, acc[mi][nj], 0, 0, 0);
            }
        }
        __syncthreads();
    }

    if (mtx < 2) {
        // q/k epilogue: fp32 raw scatter + amax (bit-identical to r6)
        float* dst = mtx == 0 ? qraw : kraw;
        float mx = 0.f;
#pragma unroll
        for (int mi = 0; mi < 4; ++mi) {
#pragma unroll
            for (int r = 0; r < 4; ++r) {
                int t = t0 + wt0 + mi * 16 + (lane >> 4) * 4 + r;
                int b = t >> 10, n = t & 1023;
#pragma unroll
                for (int nj = 0; nj < 4; ++nj) {
                    int o = o0 + wo0 + nj * 16 + fr;
                    int h = (o >> 6) & 7, d = o & 63;
                    float val = acc[mi][nj][r];
                    dst[((size_t)(b * 8 + h) * 1024 + n) * 64 + d] = val;
                    mx = fmaxf(mx, fabsf(val));
                }
            }
        }
#pragma unroll
        for (int off = 32; off > 0; off >>= 1) mx = fmaxf(mx, __shfl_down(mx, off));
        if ((tid & 63) == 0) redmax[tid >> 6] = mx;
        __syncthreads();
        if (tid == 0) {
            float m2 = fmaxf(fmaxf(redmax[0], redmax[1]), fmaxf(redmax[2], redmax[3]));
            atomicMax(&amax[mtx], __float_as_uint(m2));
        }
    } else {
        // v epilogue: direct transposed+swizzled bf16 v^T (replaces vtrans_k).
#pragma unroll
        for (int mi = 0; mi < 4; ++mi) {
            int t0r = t0 + wt0 + mi * 16 + (lane >> 4) * 4;
            int b = t0r >> 10, n0 = t0r & 1023;
            int ml = n0 & 63, mb = n0 - ml;
#pragma unroll
            for (int nj = 0; nj < 4; ++nj) {
                int o = o0 + wo0 + nj * 16 + fr;
                int h = (o >> 6) & 7, d = o & 63;
                int mlp = (ml & 7) | ((((ml >> 3) ^ d) & 7) << 3);
                ushort4 hv;
                hv.x = bf16_rne(acc[mi][nj][0]);
                hv.y = bf16_rne(acc[mi][nj][1]);
                hv.z = bf16_rne(acc[mi][nj][2]);
                hv.w = bf16_rne(acc[mi][nj][3]);
                *(ushort4*)(vt + ((size_t)((b * 8 + h) * 64 + d)) * 1024 + mb + mlp) = hv;
            }
        }
    }
}

// ---------------------------------------------------------------------------
// K2b: q AND k raw fp32 -> int8 levels as exact bf16 (grid.y=2).
// q written LINEAR; k written XOR-SWIZZLED within each 128 B row
// (chunk16 ^= n&7) so attn kernels can DMA-stage linearly and ds_read
// bank-conflict-free (T2 both-sides rule).
// ---------------------------------------------------------------------------
__global__ __launch_bounds__(256) void quant2_k(
    const float* __restrict__ qraw, const float* __restrict__ kraw,
    const unsigned int* __restrict__ amax,
    unsigned short* __restrict__ qlv, unsigned short* __restrict__ klv)
{
    int m = blockIdx.y;
    const float* raw = m ? kraw : qraw;
    unsigned short* lv = m ? klv : qlv;
    float scale = fmaxf(__uint_as_float(amax[m]) / 127.f, 1e-8f);
    int i = blockIdx.x * 256 + threadIdx.x;          // n4 = 1048576
    float4 v = ((const float4*)raw)[i];
    float l0 = fminf(fmaxf(rintf(v.x / scale), -127.f), 127.f);
    float l1 = fminf(fmaxf(rintf(v.y / scale), -127.f), 127.f);
    float l2 = fminf(fmaxf(rintf(v.z / scale), -127.f), 127.f);
    float l3 = fminf(fmaxf(rintf(v.w / scale), -127.f), 127.f);
    ushort4 o;
    o.x = bf16_exact(l0); o.y = bf16_exact(l1);
    o.z = bf16_exact(l2); o.w = bf16_exact(l3);
    int idx4 = i;
    if (m) {
        int elem0 = i * 4;
        int d0 = elem0 & 63;
        int n = (elem0 >> 6) & 1023;
        int dp = (d0 & 7) | ((((d0 >> 3) ^ n) & 7) << 3);
        idx4 = (elem0 - d0 + dp) >> 2;
    }
    ((ushort4*)lv)[idx4] = o;
}

// ---------------------------------------------------------------------------
// K3a: FUSED stats: MFMA scores + bitmask + online (m,l) over ALL 16 column
// groups in one block, keeping FOUR independent per-quarter (m,l) register
// states updated in the same ascending-ci order as the old quarter-blocks,
// then per-quarter 16-lane butterfly + the old stats_merge sequential q=0..3
// merge -> rowstats + amax_attn BIT-IDENTICAL to the split version.
// K staged once per block (was 4x). Grid (16 qt, 64 bh), XCD-chunked remap.
// ---------------------------------------------------------------------------
__global__ __launch_bounds__(256) void attn_stats_k(
    const unsigned short* __restrict__ qlv, const unsigned short* __restrict__ klv,
    const unsigned long long* __restrict__ bm, const unsigned int* __restrict__ amax,
    float2* __restrict__ rowstats, unsigned int* __restrict__ amax_attn)
{
    __shared__ __align__(16) unsigned short Ks[2][64][64];   // 16 KB dbuf
    __shared__ float redv[4];
    int tid = threadIdx.x;
    int lane = tid & 63, w = tid >> 6;
    int m_ = lane & 15, quad = lane >> 4;
    // remap (bijective on [0,1024))
    int g = blockIdx.y * 16 + blockIdx.x;
    int xcd = g & 7, slot = g >> 3;            // slot in [0,128)
    int bh = (xcd << 3) | (slot >> 4);
    int qt = slot & 15;
    int b = bh >> 3;
    int rowbase = qt * 64 + w * 16;
    float sq = fmaxf(__uint_as_float(amax[0]) / 127.f, 1e-8f);
    float sk = fmaxf(__uint_as_float(amax[1]) / 127.f, 1e-8f);
    float ss = sq * sk;

    const unsigned short* qp = qlv + ((size_t)bh * 1024 + rowbase + m_) * 64;
    short8 Aq0 = *(const short8*)(qp + quad * 8);
    short8 Aq1 = *(const short8*)(qp + 32 + quad * 8);
    const unsigned long long* bmb = bm + ((size_t)b * 1024 + rowbase) * 16;

    const unsigned short* gK = klv + ((size_t)bh * 1024 + w * 16) * 64 + lane * 8;
    int sw0 = ((quad ^ m_) & 7) << 3;          // B0 swizzled col
    int sw1 = (((4 + quad) ^ m_) & 7) << 3;    // B1

    // per-QUARTER online states (order-preserving vs the old quarter-blocks)
    float mq[4][4], lq[4][4];                  // [quarter][r]
#pragma unroll
    for (int qq = 0; qq < 4; ++qq)
#pragma unroll
        for (int r = 0; r < 4; ++r) { mq[qq][r] = -1e9f; lq[qq][r] = 0.f; }

    dma16u(gK,       &Ks[0][w * 16][0]);
    dma16u(gK + 512, &Ks[0][w * 16 + 8][0]);
    __asm__ volatile("s_waitcnt vmcnt(0)" ::: "memory");
    __builtin_amdgcn_s_barrier();

    for (int ci = 0; ci < 16; ++ci) {
        int buf = ci & 1;
        if (ci + 1 < 16) {
            size_t off = (size_t)(ci + 1) * 4096;
            dma16u(gK + off,       &Ks[buf ^ 1][w * 16][0]);
            dma16u(gK + off + 512, &Ks[buf ^ 1][w * 16 + 8][0]);
        }
        int qq = ci >> 2;
        unsigned long long mk[4];
#pragma unroll
        for (int r = 0; r < 4; ++r) mk[r] = bmb[(quad * 4 + r) * 16 + ci];
        float sv[4][4];
#pragma unroll
        for (int s = 0; s < 4; ++s) {
            short8 B0 = *(const short8*)&Ks[buf][s * 16 + m_][sw0];
            short8 B1 = *(const short8*)&Ks[buf][s * 16 + m_][sw1];
            floatx4 Cv = {0.f, 0.f, 0.f, 0.f};
            Cv = __builtin_amdgcn_mfma_f32_16x16x32_bf16(Aq0, B0, Cv, 0, 0, 0);
            Cv = __builtin_amdgcn_mfma_f32_16x16x32_bf16(Aq1, B1, Cv, 0, 0, 0);
            int colbit = s * 16 + m_;
#pragma unroll
            for (int r = 0; r < 4; ++r)
                sv[r][s] = ((mk[r] >> colbit) & 1ull) ? Cv[r] * ss : -1e9f;
        }
#pragma unroll
        for (int r = 0; r < 4; ++r) {
            float tm = fmaxf(fmaxf(sv[r][0], sv[r][1]), fmaxf(sv[r][2], sv[r][3]));
            float mn = fmaxf(mq[qq][r], tm);
            float e = __expf(sv[r][0] - mn) + __expf(sv[r][1] - mn)
                    + __expf(sv[r][2] - mn) + __expf(sv[r][3] - mn);
            lq[qq][r] = fmaf(lq[qq][r], __expf(mq[qq][r] - mn), e);
            mq[qq][r] = mn;
        }
        __asm__ volatile("s_waitcnt vmcnt(0)" ::: "memory");
        __builtin_amdgcn_s_barrier();
    }

    // per r: butterfly each quarter over 16 lanes (same as old attn_stats),
    // then old stats_merge sequential q=0..3 merge -> bit-identical rowstats.
    float iv = 0.f;
#pragma unroll
    for (int r = 0; r < 4; ++r) {
        float M[4], L[4];
#pragma unroll
        for (int qq = 0; qq < 4; ++qq) {
            float m = mq[qq][r], l = lq[qq][r];
#pragma unroll
            for (int off = 1; off < 16; off <<= 1) {
                float mo = __shfl_xor(m, off);
                float lo = __shfl_xor(l, off);
                float mn = fmaxf(m, mo);
                l = l * __expf(m - mn) + lo * __expf(mo - mn);
                m = mn;
            }
            M[qq] = m; L[qq] = l;
        }
        float m = M[0], l = L[0];
#pragma unroll
        for (int qq = 1; qq < 4; ++qq) {
            float mn = fmaxf(m, M[qq]);
            l = l * __expf(m - mn) + L[qq] * __expf(M[qq] - mn);
            m = mn;
        }
        if (m_ == 0)
            rowstats[(size_t)bh * 1024 + rowbase + quad * 4 + r] = make_float2(m, l);
        iv = fmaxf(iv, 1.0f / l);
    }
    // block-level max of 1/l -> one atomic per block (max is exact)
#pragma unroll
    for (int off = 1; off < 64; off <<= 1) iv = fmaxf(iv, __shfl_xor(iv, off));
    if (lane == 0) redv[w] = iv;
    __syncthreads();
    if (tid == 0) {
        float m2 = fmaxf(fmaxf(redv[0], redv[1]), fmaxf(redv[2], redv[3]));
        atomicMax(amax_attn, __float_as_uint(m2));
    }
}

// ---------------------------------------------------------------------------
// K3b: full-row attn+out with K AND V tiles STAGED in LDS (double-buffered
// linear DMA of pre-swizzled klv/vt, shared by 4 waves). Scores bit-identical;
// P quantize + coalesced attn writes + fused P@V MFMA; direct out store.
// XCD-chunked remap. LDS: Ks 16K + Vs 16K + pl 17.4K = 49.4 KB -> 3 blocks/CU.
// ---------------------------------------------------------------------------
__global__ __launch_bounds__(256) void attn_out_k(
    const unsigned short* __restrict__ qlv, const unsigned short* __restrict__ klv,
    const unsigned short* __restrict__ vt,
    const unsigned long long* __restrict__ bm, const unsigned int* __restrict__ amax,
    const float2* __restrict__ rowstats,
    float* __restrict__ attn, float* __restrict__ out)
{
    __shared__ __align__(16) unsigned short Ks[2][64][64];   // 16 KB
    __shared__ __align__(16) unsigned short Vs[2][64][64];   // 16 KB
    __shared__ unsigned short pl[4][2][16][68];              // per-wave P dbuf
    int tid = threadIdx.x;
    int lane = tid & 63, w = tid >> 6;
    int m_ = lane & 15, quad = lane >> 4;
    // remap (bijective on [0,1024))
    int g = blockIdx.y * 16 + blockIdx.x;
    int xcd = g & 7, slot = g >> 3;            // slot in [0,128)
    int bh = (xcd << 3) | (slot >> 4);
    int qt = slot & 15;
    int b = bh >> 3, h = bh & 7;
    int rowbase = qt * 64 + w * 16;
    float sq = fmaxf(__uint_as_float(amax[0]) / 127.f, 1e-8f);
    float sk = fmaxf(__uint_as_float(amax[1]) / 127.f, 1e-8f);
    float ss = sq * sk;
    float sa = fmaxf(__uint_as_float(amax[2]) / 127.f, 1e-8f);
    float inv_sa = 1.0f / sa;

    const unsigned short* qp = qlv + ((size_t)bh * 1024 + rowbase + m_) * 64;
    short8 Aq0 = *(const short8*)(qp + quad * 8);
    short8 Aq1 = *(const short8*)(qp + 32 + quad * 8);
    const unsigned long long* bmb = bm + ((size_t)b * 1024 + rowbase) * 16;

    // staging pointers: wave w stages tile rows [w*16, w*16+16)
    const unsigned short* gK  = klv + ((size_t)bh * 1024 + w * 16) * 64 + lane * 8;
    const unsigned short* gV  = vt + ((size_t)(bh * 64 + w * 16 + (lane >> 3))) * 1024 + (lane & 7) * 8;
    const unsigned short* gV2 = gV + 8 * 1024;
    int sw0 = ((quad ^ m_) & 7) << 3;
    int sw1 = (((4 + quad) ^ m_) & 7) << 3;

    float mrow[4], rlr[4];
#pragma unroll
    for (int r = 0; r < 4; ++r) {
        float2 st = rowstats[(size_t)bh * 1024 + rowbase + quad * 4 + r];
        mrow[r] = st.x;
        rlr[r] = 1.0f / st.y;
    }
    floatx4 acc[4];
#pragma unroll
    for (int r = 0; r < 4; ++r) acc[r] = (floatx4){0.f, 0.f, 0.f, 0.f};

    float* attn_b = attn + ((size_t)bh << 20);

#define STG(bf, cc) do {                                                  \
        dma16u(gK + (size_t)(cc) * 4096,       &Ks[bf][w * 16][0]);       \
        dma16u(gK + (size_t)(cc) * 4096 + 512, &Ks[bf][w * 16 + 8][0]);   \
        dma16u(gV + (cc) * 64,                 &Vs[bf][w * 16][0]);       \
        dma16u(gV2 + (cc) * 64,                &Vs[bf][w * 16 + 8][0]);   \
    } while (0)

    STG(0, 0);
    __asm__ volatile("s_waitcnt vmcnt(0)" ::: "memory");
    __builtin_amdgcn_s_barrier();

    for (int ci = 0; ci < 16; ++ci) {
        int c = ci;
        int buf = ci & 1;
        if (ci + 1 < 16) STG(buf ^ 1, ci + 1);
        // V fragments from LDS (buf ready via prior barrier)
        short8 Vb0[4], Vb1[4];
#pragma unroll
        for (int dt = 0; dt < 4; ++dt) {
            Vb0[dt] = *(const short8*)&Vs[buf][dt * 16 + m_][sw0];
            Vb1[dt] = *(const short8*)&Vs[buf][dt * 16 + m_][sw1];
        }
        unsigned long long mk[4];
#pragma unroll
        for (int r = 0; r < 4; ++r) mk[r] = bmb[(quad * 4 + r) * 16 + c];
        unsigned short* plw = &pl[w][ci & 1][0][0];
#pragma unroll
        for (int s = 0; s < 4; ++s) {
            short8 B0 = *(const short8*)&Ks[buf][s * 16 + m_][sw0];
            short8 B1 = *(const short8*)&Ks[buf][s * 16 + m_][sw1];
            floatx4 Cv = {0.f, 0.f, 0.f, 0.f};
            Cv = __builtin_amdgcn_mfma_f32_16x16x32_bf16(Aq0, B0, Cv, 0, 0, 0);
            Cv = __builtin_amdgcn_mfma_f32_16x16x32_bf16(Aq1, B1, Cv, 0, 0, 0);
            int colbit = s * 16 + m_;
#pragma unroll
            for (int r = 0; r < 4; ++r) {
                float sval = ((mk[r] >> colbit) & 1ull) ? Cv[r] * ss : -1e9f;
                float p = __expf(sval - mrow[r]) * rlr[r];   // round-3 op order
                float lv = fminf(rintf(p * inv_sa), 127.f);
                plw[(quad * 4 + r) * 68 + colbit] = bf16_exact(lv);
            }
        }
        __asm__ volatile("s_waitcnt lgkmcnt(0)" ::: "memory");
        short8 Ap0 = *(const short8*)&pl[w][ci & 1][m_][quad * 8];
        short8 Ap1 = *(const short8*)&pl[w][ci & 1][m_][32 + quad * 8];
#pragma unroll
        for (int dt = 0; dt < 4; ++dt) {
            acc[dt] = __builtin_amdgcn_mfma_f32_16x16x32_bf16(Ap0, Vb0[dt], acc[dt], 0, 0, 0);
            acc[dt] = __builtin_amdgcn_mfma_f32_16x16x32_bf16(Ap1, Vb1[dt], acc[dt], 0, 0, 0);
        }
        // coalesced attn write: 4 x (b64 LDS read -> float4 store, 256B rows)
#pragma unroll
        for (int it = 0; it < 4; ++it) {
            int rrow = it * 4 + quad, col = m_ * 4;
            uint2 pk = *(const uint2*)&pl[w][ci & 1][rrow][col];
            float4 av;
            av.x = bf16_to_f((unsigned short)(pk.x & 0xffff)) * sa;
            av.y = bf16_to_f((unsigned short)(pk.x >> 16)) * sa;
            av.z = bf16_to_f((unsigned short)(pk.y & 0xffff)) * sa;
            av.w = bf16_to_f((unsigned short)(pk.y >> 16)) * sa;
            *(float4*)(attn_b + (((size_t)(rowbase + rrow)) << 10) + c * 64 + col) = av;
        }
        __asm__ volatile("s_waitcnt vmcnt(0)" ::: "memory");
        __builtin_amdgcn_s_barrier();
    }
#undef STG
    // direct out store: full 1024-col accumulation done in-register
#pragma unroll
    for (int dt = 0; dt < 4; ++dt)
#pragma unroll
        for (int r = 0; r < 4; ++r) {
            int n = rowbase + quad * 4 + r;
            int d = dt * 16 + m_;
            out[(size_t)(b * 1024 + n) * 512 + h * 64 + d] = acc[dt][r] * sa;
        }
}

// ---------------------------------------------------------------------------
extern "C" void kernel_launch(void* const* d_in, const int* in_sizes, int n_in,
                              void* d_out, int out_size, void* d_ws, size_t ws_size,
                              hipStream_t stream)
{
    (void)in_sizes; (void)n_in; (void)out_size; (void)ws_size;
    const float* x   = (const float*)d_in[0];
    const int*   adj = (const int*)d_in[1];
    const float* W_q = (const float*)d_in[2];
    const float* A_q = (const float*)d_in[3];
    const float* B_q = (const float*)d_in[4];
    const float* m_q = (const float*)d_in[5];
    const float* W_k = (const float*)d_in[6];
    const float* A_k = (const float*)d_in[7];
    const float* B_k = (const float*)d_in[8];
    const float* m_k = (const float*)d_in[9];
    const float* W_v = (const float*)d_in[10];
    const float* A_v = (const float*)d_in[11];
    const float* B_v = (const float*)d_in[12];
    const float* m_v = (const float*)d_in[13];

    char* ws = (char*)d_ws;
    unsigned short* wph = (unsigned short*)(ws + OB_WPT);            // 1.5 MB
    unsigned short* wpm = (unsigned short*)(ws + OB_WPT + 1572864);  // 1.5 MB
    unsigned short* wpl = (unsigned short*)(ws + OB_WPT + 3145728);  // 1.5 MB
    unsigned short* xh  = (unsigned short*)(ws + OB_XT);             // 8.4 MB
    unsigned short* xm  = (unsigned short*)(ws + OB_XT + 8388608);   // 8.4 MB
    unsigned short* xl  = (unsigned short*)(ws + OB_XT + 16777216);  // 8.4 MB
    float* qraw         = (float*)(ws + OB_QRAW);
    float* kraw         = (float*)(ws + OB_KRAW);
    unsigned short* qlv = (unsigned short*)(ws + OB_QLV);   // overlays xh
    unsigned short* klv = (unsigned short*)(ws + OB_KLV);
    unsigned short* vt  = (unsigned short*)(ws + OB_VT);    // proj-written
    float2* rowstats    = (float2*)(ws + OB_RS);
    unsigned long long* bmask = (unsigned long long*)(ws + OB_BM);
    unsigned int* amax  = (unsigned int*)(ws + OB_AMAX);

    float* out_base  = (float*)d_out;          // (b, n, 512)
    float* attn_base = out_base + 4194304;     // (b, h, n, m)

    hipMemsetAsync(amax, 0, 16, stream);

    adj_bits_k<<<32768, 256, 0, stream>>>(adj, bmask);
    splitx_k<<<4096, 256, 0, stream>>>(x, xh, xm, xl);

    build_wp3_k<<<dim3(512, 3), 256, 0, stream>>>(W_q, A_q, B_q, m_q,
                                                  W_k, A_k, B_k, m_k,
                                                  W_v, A_v, B_v, m_v, wph, wpm, wpl);
    proj_mfma_k<<<dim3(64, 12), 256, 0, stream>>>(xh, xm, xl, wph, wpm, wpl,
                                                  qraw, kraw, vt, amax);
    quant2_k<<<dim3(4096, 2), 256, 0, stream>>>(qraw, kraw, amax, qlv, klv);

    attn_stats_k<<<dim3(16, 64), 256, 0, stream>>>(qlv, klv, bmask, amax,
                                                   rowstats, amax + 2);
    attn_out_k<<<dim3(16, 64), 256, 0, stream>>>(qlv, klv, vt, bmask, amax,
                                                 rowstats, attn_base, out_base);
}